// Round 4
// baseline (2846.815 us; speedup 1.0000x reference)
//
#include <hip/hip_runtime.h>

#define BB 128
#define NN 512
#define KNNK 4

typedef __attribute__((ext_vector_type(8))) short s8v;
typedef __attribute__((ext_vector_type(4))) float f4v;

__device__ __forceinline__ float lrelu(float v) { return v > 0.0f ? v : 0.01f * v; }

__device__ __forceinline__ unsigned short f2bf(float f) {
    unsigned int u = __float_as_uint(f);
    u += 0x7FFFu + ((u >> 16) & 1u);   // RTNE
    return (unsigned short)(u >> 16);
}
__device__ __forceinline__ float bf2f(unsigned short s) {
    return __uint_as_float(((unsigned int)s) << 16);
}

// ---------------------------------------------------------------- kNN
__global__ __launch_bounds__(512)
void knn_kernel(const float* __restrict__ feat, int ldf, int* __restrict__ idx_out) {
    __shared__ float px[NN], py[NN], pz[NN], sq[NN];
    const int b = blockIdx.x;
    const int i = threadIdx.x;
    const float* fb = feat + (size_t)b * NN * ldf;
    const float x = fb[(size_t)i * ldf + 0];
    const float y = fb[(size_t)i * ldf + 1];
    const float z = fb[(size_t)i * ldf + 2];
    px[i] = x; py[i] = y; pz[i] = z;
    const float s = x * x + y * y + z * z;
    sq[i] = s;
    __syncthreads();
    float bd0 = 3.4e38f, bd1 = 3.4e38f, bd2 = 3.4e38f, bd3 = 3.4e38f;
    int bj0 = 0, bj1 = 0, bj2 = 0, bj3 = 0;
    for (int j = 0; j < NN; j++) {
        const float d2 = s + sq[j] - 2.0f * (x * px[j] + y * py[j] + z * pz[j]);
        if (j != i && d2 < bd3) {
            if (d2 < bd2) {
                bd3 = bd2; bj3 = bj2;
                if (d2 < bd1) {
                    bd2 = bd1; bj2 = bj1;
                    if (d2 < bd0) { bd1 = bd0; bj1 = bj0; bd0 = d2; bj0 = j; }
                    else { bd1 = d2; bj1 = j; }
                } else { bd2 = d2; bj2 = j; }
            } else { bd3 = d2; bj3 = j; }
        }
    }
    int* ip = idx_out + ((size_t)b * NN + i) * KNNK;
    ip[0] = bj0; ip[1] = bj1; ip[2] = bj2; ip[3] = bj3;
}

// ---------------------------------------------------------------- conv1 (bit-exact; smaller LDS -> 3 blocks/CU)
__global__ __launch_bounds__(256, 3)
void conv1_kernel(const float* __restrict__ X,
                  const int* __restrict__ nidx,
                  const float* __restrict__ W1, const float* __restrict__ b1,
                  const float* __restrict__ W2, const float* __restrict__ b2,
                  float* __restrict__ out)
{
    __shared__ float E[8][64];
    __shared__ float W1s[8][96];
    __shared__ float h1t[96][64];
    __shared__ float W2t[16][192];
    __shared__ float b1s[96], b2s[192];

    const int t = threadIdx.x;
    const int b = blockIdx.x >> 5;
    const int nb = (blockIdx.x & 31) << 4;
    const float* Xb = X + (size_t)b * NN * 4;

    for (int i = t; i < 8 * 96; i += 256) W1s[i / 96][i % 96] = W1[i];
    if (t < 96) b1s[t] = b1[t];
    if (t < 192) b2s[t] = b2[t];

    if (t < 64) {
        const int e = t;
        const int node = nb + (e >> 2);
        const int j = nidx[((size_t)b * NN + node) * KNNK + (e & 3)];
        const float4 xi = *(const float4*)(Xb + (size_t)node * 4);
        const float4 xj = *(const float4*)(Xb + (size_t)j * 4);
        E[0][e] = xi.x; E[1][e] = xi.y; E[2][e] = xi.z; E[3][e] = xi.w;
        E[4][e] = xj.x - xi.x; E[5][e] = xj.y - xi.y; E[6][e] = xj.z - xi.z; E[7][e] = xj.w - xi.w;
    }
    __syncthreads();

    const int rg = t & 15;
    {   // GEMM1
        const int cg = t >> 4;
        float acc[4][6];
#pragma unroll
        for (int r = 0; r < 4; r++)
#pragma unroll
            for (int c = 0; c < 6; c++) acc[r][c] = 0.0f;
#pragma unroll
        for (int k = 0; k < 8; k++) {
            const float4 e4 = *(const float4*)&E[k][rg * 4];
            const float er[4] = {e4.x, e4.y, e4.z, e4.w};
            float wc[6];
#pragma unroll
            for (int c = 0; c < 6; c++) wc[c] = W1s[k][cg * 6 + c];
#pragma unroll
            for (int r = 0; r < 4; r++)
#pragma unroll
                for (int c = 0; c < 6; c++) acc[r][c] += er[r] * wc[c];
        }
#pragma unroll
        for (int c = 0; c < 6; c++) {
            const int col = cg * 6 + c;
            const float bias = b1s[col];
#pragma unroll
            for (int r = 0; r < 4; r++) h1t[col][rg * 4 + r] = lrelu(acc[r][c] + bias);
        }
    }
    __syncthreads();

    {   // GEMM2 (6 chunks of 16 rows; same ascending k order as before)
        const int cg = t >> 4;
        float acc[4][12];
#pragma unroll
        for (int r = 0; r < 4; r++)
#pragma unroll
            for (int c = 0; c < 12; c++) acc[r][c] = 0.0f;
        for (int kt = 0; kt < 6; kt++) {
            for (int i = t; i < 16 * 192; i += 256)
                W2t[i / 192][i % 192] = W2[(size_t)(kt * 16 + i / 192) * 192 + i % 192];
            __syncthreads();
#pragma unroll
            for (int kk = 0; kk < 16; kk++) {
                const int k = kt * 16 + kk;
                const float4 e4 = *(const float4*)&h1t[k][rg * 4];
                const float er[4] = {e4.x, e4.y, e4.z, e4.w};
                float wc[12];
#pragma unroll
                for (int c = 0; c < 12; c += 4) {
                    const float4 w4 = *(const float4*)&W2t[kk][cg * 12 + c];
                    wc[c] = w4.x; wc[c + 1] = w4.y; wc[c + 2] = w4.z; wc[c + 3] = w4.w;
                }
#pragma unroll
                for (int r = 0; r < 4; r++)
#pragma unroll
                    for (int c = 0; c < 12; c++) acc[r][c] += er[r] * wc[c];
            }
            __syncthreads();
        }
        const int node = nb + rg;
        float res[12];
#pragma unroll
        for (int c = 0; c < 12; c++) {
            const float bias = b2s[cg * 12 + c];
            res[c] = lrelu(acc[0][c] + bias) + lrelu(acc[1][c] + bias)
                   + lrelu(acc[2][c] + bias) + lrelu(acc[3][c] + bias);
        }
        float* op = out + ((size_t)b * NN + node) * 192 + cg * 12;
#pragma unroll
        for (int c = 0; c < 12; c += 4) {
            float4 o; o.x = res[c]; o.y = res[c + 1]; o.z = res[c + 2]; o.w = res[c + 3];
            *(float4*)(op + c) = o;
        }
    }
}

// ---------------------------------------------------------------- weight prep (conv)
__global__ void wprep_kernel(const float* __restrict__ W1, float* __restrict__ Wcat) {
    const int idx = blockIdx.x * 256 + threadIdx.x;   // 192*512
    const int k = idx >> 9;
    const int c = idx & 511;
    float v = 0.0f;
    if (c < 252) v = W1[(size_t)k * 252 + c] - W1[(size_t)(192 + k) * 252 + c];
    else if (c >= 256 && c < 508) v = W1[(size_t)(192 + k) * 252 + (c - 256)];
    Wcat[idx] = v;
}

// ---------------------------------------------------------------- PQ node GEMM (fp32, unchanged)
__global__ __launch_bounds__(256, 4)
void pq_gemm_kernel(const float* __restrict__ X,
                    const float* __restrict__ Wcat,
                    float* __restrict__ PQ)
{
    __shared__ float Xt[16][68];
    __shared__ float Wt[16][128];
    const int t = threadIdx.x;
    const int m0 = (blockIdx.x >> 2) << 6;
    const int n0 = (blockIdx.x & 3) << 7;

    const int rg = t & 15, cg = t >> 4;
    const int sm = t >> 2;
    const int skq = (t & 3) << 2;

    const int q0 = t, q1 = t + 256;
    const int kkA = q0 >> 5, c4A = (q0 & 31) << 2;
    const int kkB = q1 >> 5, c4B = (q1 & 31) << 2;

    float acc[4][8];
#pragma unroll
    for (int r = 0; r < 4; r++)
#pragma unroll
        for (int c = 0; c < 8; c++) acc[r][c] = 0.0f;

    for (int kt = 0; kt < 12; ++kt) {
        const int k0 = kt << 4;
        const float4 xv = *(const float4*)&X[(size_t)(m0 + sm) * 192 + k0 + skq];
        Xt[skq + 0][sm] = xv.x;
        Xt[skq + 1][sm] = xv.y;
        Xt[skq + 2][sm] = xv.z;
        Xt[skq + 3][sm] = xv.w;
        *(float4*)&Wt[kkA][c4A] = *(const float4*)&Wcat[(size_t)(k0 + kkA) * 512 + n0 + c4A];
        *(float4*)&Wt[kkB][c4B] = *(const float4*)&Wcat[(size_t)(k0 + kkB) * 512 + n0 + c4B];
        __syncthreads();
#pragma unroll
        for (int kk = 0; kk < 16; ++kk) {
            const float4 x4 = *(const float4*)&Xt[kk][rg * 4];
            const float4 w0 = *(const float4*)&Wt[kk][cg * 8];
            const float4 w1 = *(const float4*)&Wt[kk][cg * 8 + 4];
            const float xr[4] = {x4.x, x4.y, x4.z, x4.w};
            const float wc[8] = {w0.x, w0.y, w0.z, w0.w, w1.x, w1.y, w1.z, w1.w};
#pragma unroll
            for (int r = 0; r < 4; r++)
#pragma unroll
                for (int c = 0; c < 8; c++) acc[r][c] += xr[r] * wc[c];
        }
        __syncthreads();
    }
#pragma unroll
    for (int r = 0; r < 4; r++) {
        float* op = PQ + (size_t)(m0 + rg * 4 + r) * 512 + n0 + cg * 8;
        float4 o0; o0.x = acc[r][0]; o0.y = acc[r][1]; o0.z = acc[r][2]; o0.w = acc[r][3];
        float4 o1; o1.x = acc[r][4]; o1.y = acc[r][5]; o1.z = acc[r][6]; o1.w = acc[r][7];
        *(float4*)op = o0;
        *(float4*)(op + 4) = o1;
    }
}

// ---------------------------------------------------------------- conv2/3/4 edge phase
// v2: 32 nodes (128 edges)/block; per-output k-order identical to v1 (bit-exact).
__global__ __launch_bounds__(256, 2)
void conv234e_kernel(const float* __restrict__ PQ,
                     const int* __restrict__ nidx,
                     const float* __restrict__ W2,
                     const float* __restrict__ b1,
                     const float* __restrict__ b2,
                     float* __restrict__ out)
{
    __shared__ float h1c[16][128];   // [k][edge]
    __shared__ float Wt[16][192];
    __shared__ float b1s[256];
    __shared__ float b2s[192];

    const int t = threadIdx.x;
    const int nodebase = (blockIdx.x >> 4) << 9;
    const int nb = (blockIdx.x & 15) << 5;

    b1s[t] = (t < 252) ? b1[t] : 0.0f;
    if (t < 192) b2s[t] = b2[t];

    const int m = t >> 3;          // node 0..31 (staging AND compute role)
    const int sk = (t & 7) << 1;   // staging k pair
    const int cg = t & 7;          // col group: 24 cols

    const int4 jj = *(const int4*)&nidx[(size_t)(nodebase + nb + m) * 4];
    const float* Prow = PQ + (size_t)(nodebase + nb + m) * 512;
    const float* Q0 = PQ + (size_t)(nodebase + jj.x) * 512 + 256;
    const float* Q1 = PQ + (size_t)(nodebase + jj.y) * 512 + 256;
    const float* Q2 = PQ + (size_t)(nodebase + jj.z) * 512 + 256;
    const float* Q3 = PQ + (size_t)(nodebase + jj.w) * 512 + 256;

    // W2-stage indices (3 float4 per thread)
    const int qa = t, qb = t + 256, qc = t + 512;
    const int kka = qa / 48, ca = (qa % 48) << 2;
    const int kkb = qb / 48, cb = (qb % 48) << 2;
    const int kkc = qc / 48, cc = (qc % 48) << 2;

    float acc[4][24];
#pragma unroll
    for (int r = 0; r < 4; r++)
#pragma unroll
        for (int c = 0; c < 24; c++) acc[r][c] = 0.0f;

    __syncthreads();

    const float4 zero4 = {0.0f, 0.0f, 0.0f, 0.0f};
    for (int kt = 0; kt < 16; ++kt) {
        const int k0 = kt << 4;
        {   // h1 staging: 2 k-values x 4 edges of node m
            const int k = k0 + sk;
            const float2 pv = *(const float2*)&Prow[k];
            const float2 bb = *(const float2*)&b1s[k];
            const float2 q0 = *(const float2*)&Q0[k];
            const float2 q1 = *(const float2*)&Q1[k];
            const float2 q2 = *(const float2*)&Q2[k];
            const float2 q3 = *(const float2*)&Q3[k];
            const float p0 = pv.x + bb.x, p1 = pv.y + bb.y;
            float4 h0, h1v;
            h0.x = lrelu(p0 + q0.x); h0.y = lrelu(p0 + q1.x);
            h0.z = lrelu(p0 + q2.x); h0.w = lrelu(p0 + q3.x);
            h1v.x = lrelu(p1 + q0.y); h1v.y = lrelu(p1 + q1.y);
            h1v.z = lrelu(p1 + q2.y); h1v.w = lrelu(p1 + q3.y);
            *(float4*)&h1c[sk][m * 4] = h0;
            *(float4*)&h1c[sk + 1][m * 4] = h1v;
        }
        {   // W2 tile (rows >= 252 zero)
            const int ra = k0 + kka, rb = k0 + kkb, rc = k0 + kkc;
            *(float4*)&Wt[kka][ca] = (ra < 252) ? *(const float4*)&W2[(size_t)ra * 192 + ca] : zero4;
            *(float4*)&Wt[kkb][cb] = (rb < 252) ? *(const float4*)&W2[(size_t)rb * 192 + cb] : zero4;
            *(float4*)&Wt[kkc][cc] = (rc < 252) ? *(const float4*)&W2[(size_t)rc * 192 + cc] : zero4;
        }
        __syncthreads();
#pragma unroll
        for (int kk = 0; kk < 16; ++kk) {
            const float4 h4 = *(const float4*)&h1c[kk][m * 4];
            const float hr[4] = {h4.x, h4.y, h4.z, h4.w};
            float wc[24];
#pragma unroll
            for (int c = 0; c < 24; c += 4) {
                const float4 w4 = *(const float4*)&Wt[kk][cg * 24 + c];
                wc[c] = w4.x; wc[c + 1] = w4.y; wc[c + 2] = w4.z; wc[c + 3] = w4.w;
            }
#pragma unroll
            for (int r = 0; r < 4; r++)
#pragma unroll
                for (int c = 0; c < 24; c++) acc[r][c] += hr[r] * wc[c];
        }
        __syncthreads();
    }
    float res[24];
#pragma unroll
    for (int c = 0; c < 24; c++) {
        const float bias = b2s[cg * 24 + c];
        res[c] = lrelu(acc[0][c] + bias) + lrelu(acc[1][c] + bias)
               + lrelu(acc[2][c] + bias) + lrelu(acc[3][c] + bias);
    }
    float* op = out + (size_t)(nodebase + nb + m) * 192 + cg * 24;
#pragma unroll
    for (int c = 0; c < 24; c += 4) {
        float4 o; o.x = res[c]; o.y = res[c + 1]; o.z = res[c + 2]; o.w = res[c + 3];
        *(float4*)(op + c) = o;
    }
}

// ---------------------------------------------------------------- nn weight prep (transposed bf16 hi/lo planes)
// W1T[256 cols][800 k]: k 0..3 -> W1 rows 0..3; k 32+s*192+kk -> W1 row 4+s*192+kk; else 0
__global__ void nn1prep_kernel(const float* __restrict__ W1,
                               unsigned short* __restrict__ hi,
                               unsigned short* __restrict__ lo) {
    const int idx = blockIdx.x * 256 + threadIdx.x;  // 256*800
    const int col = idx / 800, k = idx % 800;
    float v = 0.0f;
    if (col < 252) {
        if (k < 4) v = W1[(size_t)k * 252 + col];
        else if (k >= 32) {
            const int s = (k - 32) / 192, kk = (k - 32) % 192;
            v = W1[(size_t)(4 + s * 192 + kk) * 252 + col];
        }
    }
    const unsigned short h = f2bf(v);
    hi[idx] = h;
    lo[idx] = f2bf(v - bf2f(h));
}

// N2T[192 cols][256 k]
__global__ void nn2prep_kernel(const float* __restrict__ W2,
                               unsigned short* __restrict__ hi,
                               unsigned short* __restrict__ lo) {
    const int idx = blockIdx.x * 256 + threadIdx.x;  // 192*256
    const int col = idx >> 8, k = idx & 255;
    const float v = (k < 252) ? W2[(size_t)k * 192 + col] : 0.0f;
    const unsigned short h = f2bf(v);
    hi[idx] = h;
    lo[idx] = f2bf(v - bf2f(h));
}

// ---------------------------------------------------------------- nn1 MFMA (bf16x3)
// h1[rows][256] = lrelu(concat[x|a|b|c|d] @ W1 + b1). 64 rows/block, 4 waves x 16 N-tiles.
__global__ __launch_bounds__(256)
void nn1_mfma_kernel(const float* __restrict__ x,
                     const float* __restrict__ a,
                     const float* __restrict__ bf,
                     const float* __restrict__ cf,
                     const float* __restrict__ df,
                     const unsigned short* __restrict__ w1t_hi,
                     const unsigned short* __restrict__ w1t_lo,
                     const float* __restrict__ b1,
                     float* __restrict__ h1)
{
    const int t = threadIdx.x;
    const int wv = t >> 6, l = t & 63, lm = l & 15, g = l >> 4;
    const int m0 = blockIdx.x << 6;
    const int row = m0 + wv * 16 + lm;

    f4v acc[16];
#pragma unroll
    for (int i = 0; i < 16; i++) acc[i] = (f4v){0.0f, 0.0f, 0.0f, 0.0f};

    const float* segp[4] = {a, bf, cf, df};

#pragma unroll 1
    for (int step = 0; step < 25; ++step) {
        float v[8];
        if (step == 0) {
            if (g == 0) {
                const float4 xv = *(const float4*)&x[(size_t)row * 4];
                v[0] = xv.x; v[1] = xv.y; v[2] = xv.z; v[3] = xv.w;
                v[4] = v[5] = v[6] = v[7] = 0.0f;
            } else {
#pragma unroll
                for (int i = 0; i < 8; i++) v[i] = 0.0f;
            }
        } else {
            const int s = (step - 1) / 6;
            const int kin = ((step - 1) % 6) * 32 + g * 8;
            const float* sp = segp[s] + (size_t)row * 192 + kin;
            const float4 a0 = *(const float4*)sp;
            const float4 a1 = *(const float4*)(sp + 4);
            v[0] = a0.x; v[1] = a0.y; v[2] = a0.z; v[3] = a0.w;
            v[4] = a1.x; v[5] = a1.y; v[6] = a1.z; v[7] = a1.w;
        }
        s8v ahi, alo;
#pragma unroll
        for (int i = 0; i < 8; i++) {
            const unsigned short h = f2bf(v[i]);
            ahi[i] = (short)h;
            alo[i] = (short)f2bf(v[i] - bf2f(h));
        }
        const int kb = step * 32 + g * 8;
#pragma unroll
        for (int nt = 0; nt < 16; ++nt) {
            const size_t boff = (size_t)(nt * 16 + lm) * 800 + kb;
            const s8v bhi = *(const s8v*)&w1t_hi[boff];
            const s8v blo = *(const s8v*)&w1t_lo[boff];
            acc[nt] = __builtin_amdgcn_mfma_f32_16x16x32_bf16(ahi, bhi, acc[nt], 0, 0, 0);
            acc[nt] = __builtin_amdgcn_mfma_f32_16x16x32_bf16(ahi, blo, acc[nt], 0, 0, 0);
            acc[nt] = __builtin_amdgcn_mfma_f32_16x16x32_bf16(alo, bhi, acc[nt], 0, 0, 0);
        }
    }
    // epilogue: D layout col=lane&15, row=(lane>>4)*4+reg
#pragma unroll
    for (int nt = 0; nt < 16; ++nt) {
        const int col = nt * 16 + lm;
        const float bias = (col < 252) ? b1[col] : 0.0f;
#pragma unroll
        for (int r = 0; r < 4; ++r) {
            const int orow = m0 + wv * 16 + g * 4 + r;
            h1[(size_t)orow * 256 + col] = lrelu(acc[nt][r] + bias);
        }
    }
}

// ---------------------------------------------------------------- nn2 MFMA + fused pooling
__global__ __launch_bounds__(256)
void nn2pool_mfma_kernel(const float* __restrict__ h1,
                         const unsigned short* __restrict__ n2t_hi,
                         const unsigned short* __restrict__ n2t_lo,
                         const float* __restrict__ b2,
                         int grow0,
                         float* __restrict__ partials)
{
    __shared__ float red[4][3][192];
    const int t = threadIdx.x;
    const int wv = t >> 6, l = t & 63, lm = l & 15, g = l >> 4;
    const int m0 = blockIdx.x << 6;
    const int row = m0 + wv * 16 + lm;

    f4v acc[12];
#pragma unroll
    for (int i = 0; i < 12; i++) acc[i] = (f4v){0.0f, 0.0f, 0.0f, 0.0f};

#pragma unroll 1
    for (int step = 0; step < 8; ++step) {
        const int kb = step * 32 + g * 8;
        const float* sp = h1 + (size_t)row * 256 + kb;
        const float4 a0 = *(const float4*)sp;
        const float4 a1 = *(const float4*)(sp + 4);
        const float v[8] = {a0.x, a0.y, a0.z, a0.w, a1.x, a1.y, a1.z, a1.w};
        s8v ahi, alo;
#pragma unroll
        for (int i = 0; i < 8; i++) {
            const unsigned short h = f2bf(v[i]);
            ahi[i] = (short)h;
            alo[i] = (short)f2bf(v[i] - bf2f(h));
        }
#pragma unroll
        for (int nt = 0; nt < 12; ++nt) {
            const size_t boff = (size_t)(nt * 16 + lm) * 256 + kb;
            const s8v bhi = *(const s8v*)&n2t_hi[boff];
            const s8v blo = *(const s8v*)&n2t_lo[boff];
            acc[nt] = __builtin_amdgcn_mfma_f32_16x16x32_bf16(ahi, bhi, acc[nt], 0, 0, 0);
            acc[nt] = __builtin_amdgcn_mfma_f32_16x16x32_bf16(ahi, blo, acc[nt], 0, 0, 0);
            acc[nt] = __builtin_amdgcn_mfma_f32_16x16x32_bf16(alo, bhi, acc[nt], 0, 0, 0);
        }
    }

    float mx[12], mn[12], sm[12];
#pragma unroll
    for (int nt = 0; nt < 12; ++nt) {
        const float bias = b2[nt * 16 + lm];
        const float v0 = acc[nt][0] + bias, v1 = acc[nt][1] + bias;
        const float v2 = acc[nt][2] + bias, v3 = acc[nt][3] + bias;
        mx[nt] = fmaxf(fmaxf(v0, v1), fmaxf(v2, v3));
        mn[nt] = fminf(fminf(v0, v1), fminf(v2, v3));
        sm[nt] = (v0 + v1) + (v2 + v3);
    }
#pragma unroll
    for (int nt = 0; nt < 12; ++nt) {
        mx[nt] = fmaxf(mx[nt], __shfl_xor(mx[nt], 16));
        mn[nt] = fminf(mn[nt], __shfl_xor(mn[nt], 16));
        sm[nt] += __shfl_xor(sm[nt], 16);
        mx[nt] = fmaxf(mx[nt], __shfl_xor(mx[nt], 32));
        mn[nt] = fminf(mn[nt], __shfl_xor(mn[nt], 32));
        sm[nt] += __shfl_xor(sm[nt], 32);
    }
    if (l < 16) {
#pragma unroll
        for (int nt = 0; nt < 12; ++nt) {
            const int col = nt * 16 + lm;
            red[wv][0][col] = mx[nt];
            red[wv][1][col] = mn[nt];
            red[wv][2][col] = sm[nt];
        }
    }
    __syncthreads();
    if (t < 192) {
        const int grow = grow0 + m0;
        float* pp = partials + (((size_t)(grow >> 9) * 8 + ((grow >> 6) & 7)) * 3) * 192;
        pp[t]       = fmaxf(fmaxf(red[0][0][t], red[1][0][t]), fmaxf(red[2][0][t], red[3][0][t]));
        pp[192 + t] = fminf(fminf(red[0][1][t], red[1][1][t]), fminf(red[2][1][t], red[3][1][t]));
        pp[384 + t] = (red[0][2][t] + red[1][2][t]) + (red[2][2][t] + red[3][2][t]);
    }
}

// ---------------------------------------------------------------- pool reduce (8 partials)
__global__ void pool_reduce_kernel(const float* __restrict__ partials, float* __restrict__ pooledL) {
    const int b = blockIdx.x, c = threadIdx.x;
    float mx = -3.4e38f, mn = 3.4e38f, sm = 0.0f;
    for (int blk = 0; blk < 8; blk++) {
        const float* pp = partials + ((size_t)b * 8 + blk) * 3 * 192;
        mx = fmaxf(mx, pp[c]);
        mn = fminf(mn, pp[192 + c]);
        sm += pp[384 + c];
    }
    float* o = pooledL + (size_t)b * 768;
    o[c] = lrelu(mx);
    o[192 + c] = lrelu(mn);
    o[384 + c] = lrelu(sm);
    o[576 + c] = lrelu(sm * (1.0f / 512.0f));
}

// ---------------------------------------------------------------- head
__global__ __launch_bounds__(128)
void head_kernel(const float* __restrict__ pooledL,
                 const float* __restrict__ W3, const float* __restrict__ b3,
                 const float* __restrict__ W4, const float* __restrict__ b4,
                 float* __restrict__ out) {
    __shared__ float pl[768];
    __shared__ float h3[96];
    const int b = blockIdx.x, t = threadIdx.x;
    for (int i = t; i < 768; i += 128) pl[i] = pooledL[(size_t)b * 768 + i];
    __syncthreads();
    if (t < 96) {
        float acc = b3[t];
        for (int k = 0; k < 768; k++) acc += pl[k] * W3[(size_t)k * 96 + t];
        h3[t] = lrelu(acc);
    }
    __syncthreads();
    if (t == 0) {
        float s2 = b4[0];
        for (int o = 0; o < 96; o++) s2 += h3[o] * W4[o];
        out[b] = s2;
    }
}

// ---------------------------------------------------------------- launch
extern "C" void kernel_launch(void* const* d_in, const int* in_sizes, int n_in,
                              void* d_out, int out_size, void* d_ws, size_t ws_size,
                              hipStream_t stream) {
    const float* x    = (const float*)d_in[0];
    const float* c1w1 = (const float*)d_in[1];
    const float* c1b1 = (const float*)d_in[2];
    const float* c1w2 = (const float*)d_in[3];
    const float* c1b2 = (const float*)d_in[4];
    const float* cw1[3] = {(const float*)d_in[5], (const float*)d_in[9],  (const float*)d_in[13]};
    const float* cb1[3] = {(const float*)d_in[6], (const float*)d_in[10], (const float*)d_in[14]};
    const float* cw2[3] = {(const float*)d_in[7], (const float*)d_in[11], (const float*)d_in[15]};
    const float* cb2[3] = {(const float*)d_in[8], (const float*)d_in[12], (const float*)d_in[16]};
    const float* nn1w = (const float*)d_in[17];
    const float* nn1b = (const float*)d_in[18];
    const float* nn2w = (const float*)d_in[19];
    const float* nn2b = (const float*)d_in[20];
    const float* nn3w = (const float*)d_in[21];
    const float* nn3b = (const float*)d_in[22];
    const float* nn4w = (const float*)d_in[23];
    const float* nn4b = (const float*)d_in[24];
    float* out = (float*)d_out;

    // workspace layout (float units)
    const size_t featN  = (size_t)BB * NN * 192;
    const size_t idx_f  = (size_t)BB * NN * KNNK;
    const size_t part_f = (size_t)BB * 8 * 3 * 192;
    const size_t pool_f = (size_t)BB * 768;
    const size_t wcat_f = (size_t)192 * 512;
    const size_t w1t_f  = (size_t)256 * 800 / 2;   // ushort plane in float units
    const size_t n2t_f  = (size_t)192 * 256 / 2;

    float* abuf = (float*)d_ws;
    float* bbuf = abuf + featN;
    float* cbuf = bbuf + featN;
    float* dbuf = cbuf + featN;
    int*   idxb = (int*)(dbuf + featN);
    float* partials = (float*)(idxb + idx_f);
    float* pooledL = partials + part_f;
    float* wcat = pooledL + pool_f;
    unsigned short* w1t_hi = (unsigned short*)(wcat + wcat_f);
    unsigned short* w1t_lo = (unsigned short*)(wcat + wcat_f + w1t_f);
    unsigned short* n2t_hi = (unsigned short*)(wcat + wcat_f + 2 * w1t_f);
    unsigned short* n2t_lo = (unsigned short*)(wcat + wcat_f + 2 * w1t_f + n2t_f);
    float* pqbuf = wcat + wcat_f + 2 * w1t_f + 2 * n2t_f;

    const size_t fixed_f = 4 * featN + idx_f + part_f + pool_f + wcat_f + 2 * w1t_f + 2 * n2t_f;
    int CB = BB;
    while (CB > 1) {
        const size_t need = (fixed_f + (size_t)CB * NN * 512) * 4;
        if (need <= ws_size) break;
        CB >>= 1;
    }
    const int nchunks = BB / CB;

    float* feats[4] = {abuf, bbuf, cbuf, dbuf};

    knn_kernel<<<BB, 512, 0, stream>>>(x, 4, idxb);
    conv1_kernel<<<BB * 32, 256, 0, stream>>>(x, idxb, c1w1, c1b1, c1w2, c1b2, abuf);

    for (int L = 0; L < 3; ++L) {
        const float* fin = feats[L];
        float* fout = feats[L + 1];
        knn_kernel<<<BB, 512, 0, stream>>>(fin, 192, idxb);
        wprep_kernel<<<(192 * 512) / 256, 256, 0, stream>>>(cw1[L], wcat);
        for (int ch = 0; ch < nchunks; ++ch) {
            const size_t roff = (size_t)ch * CB * NN;
            pq_gemm_kernel<<<CB * 32, 256, 0, stream>>>(fin + roff * 192, wcat, pqbuf);
            conv234e_kernel<<<CB * 16, 256, 0, stream>>>(pqbuf, idxb + roff * KNNK,
                                                         cw2[L], cb1[L], cb2[L],
                                                         fout + roff * 192);
        }
    }

    // nn phase (MFMA bf16x3); h1 reuses pqbuf (CB*512*256 <= CB*512*512)
    nn1prep_kernel<<<(256 * 800) / 256, 256, 0, stream>>>(nn1w, w1t_hi, w1t_lo);
    nn2prep_kernel<<<(192 * 256) / 256, 256, 0, stream>>>(nn2w, n2t_hi, n2t_lo);
    float* h1buf = pqbuf;
    for (int ch = 0; ch < nchunks; ++ch) {
        const size_t roff = (size_t)ch * CB * NN;
        nn1_mfma_kernel<<<CB * 8, 256, 0, stream>>>(x + roff * 4,
                                                    abuf + roff * 192, bbuf + roff * 192,
                                                    cbuf + roff * 192, dbuf + roff * 192,
                                                    w1t_hi, w1t_lo, nn1b, h1buf);
        nn2pool_mfma_kernel<<<CB * 8, 256, 0, stream>>>(h1buf, n2t_hi, n2t_lo, nn2b,
                                                        (int)roff, partials);
    }
    pool_reduce_kernel<<<BB, 192, 0, stream>>>(partials, pooledL);
    head_kernel<<<BB, 128, 0, stream>>>(pooledL, nn3w, nn3b, nn4w, nn4b, out);
}

// Round 5
// 2422.268 us; speedup vs baseline: 1.1753x; 1.1753x over previous
//
#include <hip/hip_runtime.h>

#define BB 128
#define NN 512
#define KNNK 4

typedef __attribute__((ext_vector_type(8))) short s8v;
typedef __attribute__((ext_vector_type(4))) float f4v;

__device__ __forceinline__ float lrelu(float v) { return v > 0.0f ? v : 0.01f * v; }

__device__ __forceinline__ unsigned short f2bf(float f) {
    unsigned int u = __float_as_uint(f);
    u += 0x7FFFu + ((u >> 16) & 1u);   // RTNE
    return (unsigned short)(u >> 16);
}
__device__ __forceinline__ float bf2f(unsigned short s) {
    return __uint_as_float(((unsigned int)s) << 16);
}

// ---------------------------------------------------------------- kNN
__global__ __launch_bounds__(512)
void knn_kernel(const float* __restrict__ feat, int ldf, int* __restrict__ idx_out) {
    __shared__ float px[NN], py[NN], pz[NN], sq[NN];
    const int b = blockIdx.x;
    const int i = threadIdx.x;
    const float* fb = feat + (size_t)b * NN * ldf;
    const float x = fb[(size_t)i * ldf + 0];
    const float y = fb[(size_t)i * ldf + 1];
    const float z = fb[(size_t)i * ldf + 2];
    px[i] = x; py[i] = y; pz[i] = z;
    const float s = x * x + y * y + z * z;
    sq[i] = s;
    __syncthreads();
    float bd0 = 3.4e38f, bd1 = 3.4e38f, bd2 = 3.4e38f, bd3 = 3.4e38f;
    int bj0 = 0, bj1 = 0, bj2 = 0, bj3 = 0;
    for (int j = 0; j < NN; j++) {
        const float d2 = s + sq[j] - 2.0f * (x * px[j] + y * py[j] + z * pz[j]);
        if (j != i && d2 < bd3) {
            if (d2 < bd2) {
                bd3 = bd2; bj3 = bj2;
                if (d2 < bd1) {
                    bd2 = bd1; bj2 = bj1;
                    if (d2 < bd0) { bd1 = bd0; bj1 = bj0; bd0 = d2; bj0 = j; }
                    else { bd1 = d2; bj1 = j; }
                } else { bd2 = d2; bj2 = j; }
            } else { bd3 = d2; bj3 = j; }
        }
    }
    int* ip = idx_out + ((size_t)b * NN + i) * KNNK;
    ip[0] = bj0; ip[1] = bj1; ip[2] = bj2; ip[3] = bj3;
}

// ---------------------------------------------------------------- conv1 (R2 version: measured fastest)
__global__ __launch_bounds__(256, 2)
void conv1_kernel(const float* __restrict__ X,
                  const int* __restrict__ nidx,
                  const float* __restrict__ W1, const float* __restrict__ b1,
                  const float* __restrict__ W2, const float* __restrict__ b2,
                  float* __restrict__ out)
{
    __shared__ float E[8][64];
    __shared__ float W1s[8][96];
    __shared__ float h1t[96][64];
    __shared__ float W2t[32][192];
    __shared__ float b1s[96], b2s[192];

    const int t = threadIdx.x;
    const int b = blockIdx.x >> 5;
    const int nb = (blockIdx.x & 31) << 4;
    const float* Xb = X + (size_t)b * NN * 4;

    for (int i = t; i < 8 * 96; i += 256) W1s[i / 96][i % 96] = W1[i];
    if (t < 96) b1s[t] = b1[t];
    if (t < 192) b2s[t] = b2[t];

    if (t < 64) {
        const int e = t;
        const int node = nb + (e >> 2);
        const int j = nidx[((size_t)b * NN + node) * KNNK + (e & 3)];
        const float4 xi = *(const float4*)(Xb + (size_t)node * 4);
        const float4 xj = *(const float4*)(Xb + (size_t)j * 4);
        E[0][e] = xi.x; E[1][e] = xi.y; E[2][e] = xi.z; E[3][e] = xi.w;
        E[4][e] = xj.x - xi.x; E[5][e] = xj.y - xi.y; E[6][e] = xj.z - xi.z; E[7][e] = xj.w - xi.w;
    }
    __syncthreads();

    const int rg = t & 15;
    {   // GEMM1
        const int cg = t >> 4;
        float acc[4][6];
#pragma unroll
        for (int r = 0; r < 4; r++)
#pragma unroll
            for (int c = 0; c < 6; c++) acc[r][c] = 0.0f;
#pragma unroll
        for (int k = 0; k < 8; k++) {
            const float4 e4 = *(const float4*)&E[k][rg * 4];
            const float er[4] = {e4.x, e4.y, e4.z, e4.w};
            float wc[6];
#pragma unroll
            for (int c = 0; c < 6; c++) wc[c] = W1s[k][cg * 6 + c];
#pragma unroll
            for (int r = 0; r < 4; r++)
#pragma unroll
                for (int c = 0; c < 6; c++) acc[r][c] += er[r] * wc[c];
        }
#pragma unroll
        for (int c = 0; c < 6; c++) {
            const int col = cg * 6 + c;
            const float bias = b1s[col];
#pragma unroll
            for (int r = 0; r < 4; r++) h1t[col][rg * 4 + r] = lrelu(acc[r][c] + bias);
        }
    }
    __syncthreads();

    {   // GEMM2
        const int cg = t >> 4;
        float acc[4][12];
#pragma unroll
        for (int r = 0; r < 4; r++)
#pragma unroll
            for (int c = 0; c < 12; c++) acc[r][c] = 0.0f;
        for (int kt = 0; kt < 3; kt++) {
            for (int i = t; i < 32 * 192; i += 256)
                W2t[i / 192][i % 192] = W2[(size_t)(kt * 32 + i / 192) * 192 + i % 192];
            __syncthreads();
#pragma unroll
            for (int kk = 0; kk < 32; kk++) {
                const int k = kt * 32 + kk;
                const float4 e4 = *(const float4*)&h1t[k][rg * 4];
                const float er[4] = {e4.x, e4.y, e4.z, e4.w};
                float wc[12];
#pragma unroll
                for (int c = 0; c < 12; c += 4) {
                    const float4 w4 = *(const float4*)&W2t[kk][cg * 12 + c];
                    wc[c] = w4.x; wc[c + 1] = w4.y; wc[c + 2] = w4.z; wc[c + 3] = w4.w;
                }
#pragma unroll
                for (int r = 0; r < 4; r++)
#pragma unroll
                    for (int c = 0; c < 12; c++) acc[r][c] += er[r] * wc[c];
            }
            __syncthreads();
        }
        const int node = nb + rg;
        float res[12];
#pragma unroll
        for (int c = 0; c < 12; c++) {
            const float bias = b2s[cg * 12 + c];
            res[c] = lrelu(acc[0][c] + bias) + lrelu(acc[1][c] + bias)
                   + lrelu(acc[2][c] + bias) + lrelu(acc[3][c] + bias);
        }
        float* op = out + ((size_t)b * NN + node) * 192 + cg * 12;
#pragma unroll
        for (int c = 0; c < 12; c += 4) {
            float4 o; o.x = res[c]; o.y = res[c + 1]; o.z = res[c + 2]; o.w = res[c + 3];
            *(float4*)(op + c) = o;
        }
    }
}

// ---------------------------------------------------------------- weight prep (conv: fp32 Wcat for pq)
__global__ void wprep_kernel(const float* __restrict__ W1, float* __restrict__ Wcat) {
    const int idx = blockIdx.x * 256 + threadIdx.x;   // 192*512
    const int k = idx >> 9;
    const int c = idx & 511;
    float v = 0.0f;
    if (c < 252) v = W1[(size_t)k * 252 + c] - W1[(size_t)(192 + k) * 252 + c];
    else if (c >= 256 && c < 508) v = W1[(size_t)(192 + k) * 252 + (c - 256)];
    Wcat[idx] = v;
}

// ---------------------------------------------------------------- weight prep 2 (conv W2 -> 3 bf16 planes, transposed [col][k])
__global__ void wprep2_kernel(const float* __restrict__ W2, unsigned short* __restrict__ w2p) {
    const int idx = blockIdx.x * 256 + threadIdx.x;  // 192*256
    const int col = idx >> 8, k = idx & 255;
    const float v = (k < 252) ? W2[(size_t)k * 192 + col] : 0.0f;
    const unsigned short c0 = f2bf(v);
    const float r1 = v - bf2f(c0);
    const unsigned short c1 = f2bf(r1);
    const float r2 = r1 - bf2f(c1);
    w2p[idx] = c0;
    w2p[49152 + idx] = c1;
    w2p[98304 + idx] = f2bf(r2);
}

// ---------------------------------------------------------------- PQ node GEMM (fp32, feeds kNN cone: keep exact)
__global__ __launch_bounds__(256, 4)
void pq_gemm_kernel(const float* __restrict__ X,
                    const float* __restrict__ Wcat,
                    float* __restrict__ PQ)
{
    __shared__ float Xt[16][68];
    __shared__ float Wt[16][128];
    const int t = threadIdx.x;
    const int m0 = (blockIdx.x >> 2) << 6;
    const int n0 = (blockIdx.x & 3) << 7;

    const int rg = t & 15, cg = t >> 4;
    const int sm = t >> 2;
    const int skq = (t & 3) << 2;

    const int q0 = t, q1 = t + 256;
    const int kkA = q0 >> 5, c4A = (q0 & 31) << 2;
    const int kkB = q1 >> 5, c4B = (q1 & 31) << 2;

    float acc[4][8];
#pragma unroll
    for (int r = 0; r < 4; r++)
#pragma unroll
        for (int c = 0; c < 8; c++) acc[r][c] = 0.0f;

    for (int kt = 0; kt < 12; ++kt) {
        const int k0 = kt << 4;
        const float4 xv = *(const float4*)&X[(size_t)(m0 + sm) * 192 + k0 + skq];
        Xt[skq + 0][sm] = xv.x;
        Xt[skq + 1][sm] = xv.y;
        Xt[skq + 2][sm] = xv.z;
        Xt[skq + 3][sm] = xv.w;
        *(float4*)&Wt[kkA][c4A] = *(const float4*)&Wcat[(size_t)(k0 + kkA) * 512 + n0 + c4A];
        *(float4*)&Wt[kkB][c4B] = *(const float4*)&Wcat[(size_t)(k0 + kkB) * 512 + n0 + c4B];
        __syncthreads();
#pragma unroll
        for (int kk = 0; kk < 16; ++kk) {
            const float4 x4 = *(const float4*)&Xt[kk][rg * 4];
            const float4 w0 = *(const float4*)&Wt[kk][cg * 8];
            const float4 w1 = *(const float4*)&Wt[kk][cg * 8 + 4];
            const float xr[4] = {x4.x, x4.y, x4.z, x4.w};
            const float wc[8] = {w0.x, w0.y, w0.z, w0.w, w1.x, w1.y, w1.z, w1.w};
#pragma unroll
            for (int r = 0; r < 4; r++)
#pragma unroll
                for (int c = 0; c < 8; c++) acc[r][c] += xr[r] * wc[c];
        }
        __syncthreads();
    }
#pragma unroll
    for (int r = 0; r < 4; r++) {
        float* op = PQ + (size_t)(m0 + rg * 4 + r) * 512 + n0 + cg * 8;
        float4 o0; o0.x = acc[r][0]; o0.y = acc[r][1]; o0.z = acc[r][2]; o0.w = acc[r][3];
        float4 o1; o1.x = acc[r][4]; o1.y = acc[r][5]; o1.z = acc[r][6]; o1.w = acc[r][7];
        *(float4*)op = o0;
        *(float4*)(op + 4) = o1;
    }
}

// ---------------------------------------------------------------- conv2/3/4 edge phase: bf16x6 MFMA
// 32 nodes (128 edges)/block, 256 thr = 4 waves. M=128, N=192, K=256.
// Wave (w): mhalf=w&1 (edge half), nhalf=w>>1 (col half); 4 M-tiles x 6 N-tiles.
__global__ __launch_bounds__(256, 2)
void conv234e_mfma_kernel(const float* __restrict__ PQ,
                          const int* __restrict__ nidx,
                          const unsigned short* __restrict__ w2p,  // 3 planes [192][256]
                          const float* __restrict__ b1,
                          const float* __restrict__ b2,
                          float* __restrict__ out)
{
    __shared__ float h1c[32][132];                 // fp32 h1 tile [k][edge], padded
    __shared__ unsigned short Bl[3][192][32];      // W2 bf16 planes, XOR-swizzled 16B chunks
    __shared__ float b1s[256];
    __shared__ float b2s[192];

    const int t = threadIdx.x;
    const int nodebase = (blockIdx.x >> 4) << 9;
    const int nb = (blockIdx.x & 15) << 5;

    b1s[t] = (t < 252) ? b1[t] : 0.0f;
    if (t < 192) b2s[t] = b2[t];

    // staging roles (A): thread -> node m, k-quad s
    const int m = t >> 3, s = t & 7;
    const int4 jj = *(const int4*)&nidx[(size_t)(nodebase + nb + m) * 4];
    const float* Prow = PQ + (size_t)(nodebase + nb + m) * 512;
    const float* Q0 = PQ + (size_t)(nodebase + jj.x) * 512 + 256;
    const float* Q1 = PQ + (size_t)(nodebase + jj.y) * 512 + 256;
    const float* Q2 = PQ + (size_t)(nodebase + jj.z) * 512 + 256;
    const float* Q3 = PQ + (size_t)(nodebase + jj.w) * 512 + 256;

    // staging roles (B)
    const int bcol = t >> 2, bchk = t & 3;

    // compute roles
    const int w = t >> 6, l = t & 63, lm = l & 15, g = l >> 4;
    const int mhalf = w & 1, nhalf = w >> 1;

    f4v acc[4][6];
#pragma unroll
    for (int i = 0; i < 4; i++)
#pragma unroll
        for (int j = 0; j < 6; j++) acc[i][j] = (f4v){0.0f, 0.0f, 0.0f, 0.0f};

    __syncthreads();   // b1s ready

    for (int kt = 0; kt < 8; ++kt) {
        const int k0 = kt << 5;
        {   // ---- stage A: h1 fp32, 4 k x 4 edges per thread
            const int kq = s << 2;
            const float4 pv = *(const float4*)&Prow[k0 + kq];
            const float4 bb = *(const float4*)&b1s[k0 + kq];
            const float4 qa = *(const float4*)&Q0[k0 + kq];
            const float4 qb = *(const float4*)&Q1[k0 + kq];
            const float4 qc = *(const float4*)&Q2[k0 + kq];
            const float4 qd = *(const float4*)&Q3[k0 + kq];
            const float p0 = pv.x + bb.x, p1 = pv.y + bb.y, p2 = pv.z + bb.z, p3 = pv.w + bb.w;
            float4 h;
            h.x = lrelu(p0 + qa.x); h.y = lrelu(p0 + qb.x); h.z = lrelu(p0 + qc.x); h.w = lrelu(p0 + qd.x);
            *(float4*)&h1c[kq + 0][m * 4] = h;
            h.x = lrelu(p1 + qa.y); h.y = lrelu(p1 + qb.y); h.z = lrelu(p1 + qc.y); h.w = lrelu(p1 + qd.y);
            *(float4*)&h1c[kq + 1][m * 4] = h;
            h.x = lrelu(p2 + qa.z); h.y = lrelu(p2 + qb.z); h.z = lrelu(p2 + qc.z); h.w = lrelu(p2 + qd.z);
            *(float4*)&h1c[kq + 2][m * 4] = h;
            h.x = lrelu(p3 + qa.w); h.y = lrelu(p3 + qb.w); h.z = lrelu(p3 + qc.w); h.w = lrelu(p3 + qd.w);
            *(float4*)&h1c[kq + 3][m * 4] = h;
        }
#pragma unroll
        for (int it = 0; it < 9; ++it) {   // ---- stage B: 3 planes x 192 cols x 4 chunks
            const int p = it / 3;
            const int col = (it % 3) * 64 + bcol;
            const int pos = bchk ^ ((col >> 1) & 3);
            *(s8v*)&Bl[p][col][pos * 8] =
                *(const s8v*)&w2p[(size_t)p * 49152 + (size_t)col * 256 + k0 + bchk * 8];
        }
        __syncthreads();

        // ---- A fragments: read fp32, 3-way bf16 split (exact)
        s8v A0[4], A1[4], A2[4];
#pragma unroll
        for (int mt = 0; mt < 4; ++mt) {
            const int edge = mhalf * 64 + mt * 16 + lm;
#pragma unroll
            for (int i = 0; i < 8; ++i) {
                const float hv = h1c[g * 8 + i][edge];
                const unsigned short c0 = f2bf(hv);
                const float r1 = hv - bf2f(c0);
                const unsigned short c1 = f2bf(r1);
                const float r2 = r1 - bf2f(c1);
                A0[mt][i] = (short)c0;
                A1[mt][i] = (short)c1;
                A2[mt][i] = (short)f2bf(r2);
            }
        }
        // ---- B fragments + 6-product MFMA
#pragma unroll
        for (int nt = 0; nt < 6; ++nt) {
            const int col = nhalf * 96 + nt * 16 + lm;
            const int pos = g ^ ((col >> 1) & 3);
            const s8v B0 = *(const s8v*)&Bl[0][col][pos * 8];
            const s8v B1 = *(const s8v*)&Bl[1][col][pos * 8];
            const s8v B2 = *(const s8v*)&Bl[2][col][pos * 8];
#pragma unroll
            for (int mt = 0; mt < 4; ++mt) {
                acc[mt][nt] = __builtin_amdgcn_mfma_f32_16x16x32_bf16(A0[mt], B0, acc[mt][nt], 0, 0, 0);
                acc[mt][nt] = __builtin_amdgcn_mfma_f32_16x16x32_bf16(A0[mt], B1, acc[mt][nt], 0, 0, 0);
                acc[mt][nt] = __builtin_amdgcn_mfma_f32_16x16x32_bf16(A1[mt], B0, acc[mt][nt], 0, 0, 0);
                acc[mt][nt] = __builtin_amdgcn_mfma_f32_16x16x32_bf16(A1[mt], B1, acc[mt][nt], 0, 0, 0);
                acc[mt][nt] = __builtin_amdgcn_mfma_f32_16x16x32_bf16(A0[mt], B2, acc[mt][nt], 0, 0, 0);
                acc[mt][nt] = __builtin_amdgcn_mfma_f32_16x16x32_bf16(A2[mt], B0, acc[mt][nt], 0, 0, 0);
            }
        }
        __syncthreads();
    }

    // ---- epilogue: bias + lrelu + neighbor-sum (D rows g*4+r are the 4 edges of one node)
#pragma unroll
    for (int mt = 0; mt < 4; ++mt) {
        const int node = nodebase + nb + mhalf * 16 + mt * 4 + g;
#pragma unroll
        for (int nt = 0; nt < 6; ++nt) {
            const int col = nhalf * 96 + nt * 16 + lm;
            const float bias = b2s[col];
            const f4v v = acc[mt][nt];
            out[(size_t)node * 192 + col] =
                lrelu(v[0] + bias) + lrelu(v[1] + bias) + lrelu(v[2] + bias) + lrelu(v[3] + bias);
        }
    }
}

// ---------------------------------------------------------------- nn weight prep (transposed bf16 hi/lo planes)
__global__ void nn1prep_kernel(const float* __restrict__ W1,
                               unsigned short* __restrict__ hi,
                               unsigned short* __restrict__ lo) {
    const int idx = blockIdx.x * 256 + threadIdx.x;  // 256*800
    const int col = idx / 800, k = idx % 800;
    float v = 0.0f;
    if (col < 252) {
        if (k < 4) v = W1[(size_t)k * 252 + col];
        else if (k >= 32) {
            const int s = (k - 32) / 192, kk = (k - 32) % 192;
            v = W1[(size_t)(4 + s * 192 + kk) * 252 + col];
        }
    }
    const unsigned short h = f2bf(v);
    hi[idx] = h;
    lo[idx] = f2bf(v - bf2f(h));
}

__global__ void nn2prep_kernel(const float* __restrict__ W2,
                               unsigned short* __restrict__ hi,
                               unsigned short* __restrict__ lo) {
    const int idx = blockIdx.x * 256 + threadIdx.x;  // 192*256
    const int col = idx >> 8, k = idx & 255;
    const float v = (k < 252) ? W2[(size_t)k * 192 + col] : 0.0f;
    const unsigned short h = f2bf(v);
    hi[idx] = h;
    lo[idx] = f2bf(v - bf2f(h));
}

// ---------------------------------------------------------------- nn1 MFMA (bf16x3)
__global__ __launch_bounds__(256)
void nn1_mfma_kernel(const float* __restrict__ x,
                     const float* __restrict__ a,
                     const float* __restrict__ bf,
                     const float* __restrict__ cf,
                     const float* __restrict__ df,
                     const unsigned short* __restrict__ w1t_hi,
                     const unsigned short* __restrict__ w1t_lo,
                     const float* __restrict__ b1,
                     float* __restrict__ h1)
{
    const int t = threadIdx.x;
    const int wv = t >> 6, l = t & 63, lm = l & 15, g = l >> 4;
    const int m0 = blockIdx.x << 6;
    const int row = m0 + wv * 16 + lm;

    f4v acc[16];
#pragma unroll
    for (int i = 0; i < 16; i++) acc[i] = (f4v){0.0f, 0.0f, 0.0f, 0.0f};

    const float* segp[4] = {a, bf, cf, df};

#pragma unroll 1
    for (int step = 0; step < 25; ++step) {
        float v[8];
        if (step == 0) {
            if (g == 0) {
                const float4 xv = *(const float4*)&x[(size_t)row * 4];
                v[0] = xv.x; v[1] = xv.y; v[2] = xv.z; v[3] = xv.w;
                v[4] = v[5] = v[6] = v[7] = 0.0f;
            } else {
#pragma unroll
                for (int i = 0; i < 8; i++) v[i] = 0.0f;
            }
        } else {
            const int s = (step - 1) / 6;
            const int kin = ((step - 1) % 6) * 32 + g * 8;
            const float* sp = segp[s] + (size_t)row * 192 + kin;
            const float4 a0 = *(const float4*)sp;
            const float4 a1 = *(const float4*)(sp + 4);
            v[0] = a0.x; v[1] = a0.y; v[2] = a0.z; v[3] = a0.w;
            v[4] = a1.x; v[5] = a1.y; v[6] = a1.z; v[7] = a1.w;
        }
        s8v ahi, alo;
#pragma unroll
        for (int i = 0; i < 8; i++) {
            const unsigned short h = f2bf(v[i]);
            ahi[i] = (short)h;
            alo[i] = (short)f2bf(v[i] - bf2f(h));
        }
        const int kb = step * 32 + g * 8;
#pragma unroll
        for (int nt = 0; nt < 16; ++nt) {
            const size_t boff = (size_t)(nt * 16 + lm) * 800 + kb;
            const s8v bhi = *(const s8v*)&w1t_hi[boff];
            const s8v blo = *(const s8v*)&w1t_lo[boff];
            acc[nt] = __builtin_amdgcn_mfma_f32_16x16x32_bf16(ahi, bhi, acc[nt], 0, 0, 0);
            acc[nt] = __builtin_amdgcn_mfma_f32_16x16x32_bf16(ahi, blo, acc[nt], 0, 0, 0);
            acc[nt] = __builtin_amdgcn_mfma_f32_16x16x32_bf16(alo, bhi, acc[nt], 0, 0, 0);
        }
    }
#pragma unroll
    for (int nt = 0; nt < 16; ++nt) {
        const int col = nt * 16 + lm;
        const float bias = (col < 252) ? b1[col] : 0.0f;
#pragma unroll
        for (int r = 0; r < 4; ++r) {
            const int orow = m0 + wv * 16 + g * 4 + r;
            h1[(size_t)orow * 256 + col] = lrelu(acc[nt][r] + bias);
        }
    }
}

// ---------------------------------------------------------------- nn2 MFMA + fused pooling
__global__ __launch_bounds__(256)
void nn2pool_mfma_kernel(const float* __restrict__ h1,
                         const unsigned short* __restrict__ n2t_hi,
                         const unsigned short* __restrict__ n2t_lo,
                         const float* __restrict__ b2,
                         int grow0,
                         float* __restrict__ partials)
{
    __shared__ float red[4][3][192];
    const int t = threadIdx.x;
    const int wv = t >> 6, l = t & 63, lm = l & 15, g = l >> 4;
    const int m0 = blockIdx.x << 6;
    const int row = m0 + wv * 16 + lm;

    f4v acc[12];
#pragma unroll
    for (int i = 0; i < 12; i++) acc[i] = (f4v){0.0f, 0.0f, 0.0f, 0.0f};

#pragma unroll 1
    for (int step = 0; step < 8; ++step) {
        const int kb = step * 32 + g * 8;
        const float* sp = h1 + (size_t)row * 256 + kb;
        const float4 a0 = *(const float4*)sp;
        const float4 a1 = *(const float4*)(sp + 4);
        const float v[8] = {a0.x, a0.y, a0.z, a0.w, a1.x, a1.y, a1.z, a1.w};
        s8v ahi, alo;
#pragma unroll
        for (int i = 0; i < 8; i++) {
            const unsigned short h = f2bf(v[i]);
            ahi[i] = (short)h;
            alo[i] = (short)f2bf(v[i] - bf2f(h));
        }
#pragma unroll
        for (int nt = 0; nt < 12; ++nt) {
            const size_t boff = (size_t)(nt * 16 + lm) * 256 + kb;
            const s8v bhi = *(const s8v*)&n2t_hi[boff];
            const s8v blo = *(const s8v*)&n2t_lo[boff];
            acc[nt] = __builtin_amdgcn_mfma_f32_16x16x32_bf16(ahi, bhi, acc[nt], 0, 0, 0);
            acc[nt] = __builtin_amdgcn_mfma_f32_16x16x32_bf16(ahi, blo, acc[nt], 0, 0, 0);
            acc[nt] = __builtin_amdgcn_mfma_f32_16x16x32_bf16(alo, bhi, acc[nt], 0, 0, 0);
        }
    }

    float mx[12], mn[12], sm[12];
#pragma unroll
    for (int nt = 0; nt < 12; ++nt) {
        const float bias = b2[nt * 16 + lm];
        const float v0 = acc[nt][0] + bias, v1 = acc[nt][1] + bias;
        const float v2 = acc[nt][2] + bias, v3 = acc[nt][3] + bias;
        mx[nt] = fmaxf(fmaxf(v0, v1), fmaxf(v2, v3));
        mn[nt] = fminf(fminf(v0, v1), fminf(v2, v3));
        sm[nt] = (v0 + v1) + (v2 + v3);
    }
#pragma unroll
    for (int nt = 0; nt < 12; ++nt) {
        mx[nt] = fmaxf(mx[nt], __shfl_xor(mx[nt], 16));
        mn[nt] = fminf(mn[nt], __shfl_xor(mn[nt], 16));
        sm[nt] += __shfl_xor(sm[nt], 16);
        mx[nt] = fmaxf(mx[nt], __shfl_xor(mx[nt], 32));
        mn[nt] = fminf(mn[nt], __shfl_xor(mn[nt], 32));
        sm[nt] += __shfl_xor(sm[nt], 32);
    }
    if (l < 16) {
#pragma unroll
        for (int nt = 0; nt < 12; ++nt) {
            const int col = nt * 16 + lm;
            red[wv][0][col] = mx[nt];
            red[wv][1][col] = mn[nt];
            red[wv][2][col] = sm[nt];
        }
    }
    __syncthreads();
    if (t < 192) {
        const int grow = grow0 + m0;
        float* pp = partials + (((size_t)(grow >> 9) * 8 + ((grow >> 6) & 7)) * 3) * 192;
        pp[t]       = fmaxf(fmaxf(red[0][0][t], red[1][0][t]), fmaxf(red[2][0][t], red[3][0][t]));
        pp[192 + t] = fminf(fminf(red[0][1][t], red[1][1][t]), fminf(red[2][1][t], red[3][1][t]));
        pp[384 + t] = (red[0][2][t] + red[1][2][t]) + (red[2][2][t] + red[3][2][t]);
    }
}

// ---------------------------------------------------------------- pool reduce (8 partials)
__global__ void pool_reduce_kernel(const float* __restrict__ partials, float* __restrict__ pooledL) {
    const int b = blockIdx.x, c = threadIdx.x;
    float mx = -3.4e38f, mn = 3.4e38f, sm = 0.0f;
    for (int blk = 0; blk < 8; blk++) {
        const float* pp = partials + ((size_t)b * 8 + blk) * 3 * 192;
        mx = fmaxf(mx, pp[c]);
        mn = fminf(mn, pp[192 + c]);
        sm += pp[384 + c];
    }
    float* o = pooledL + (size_t)b * 768;
    o[c] = lrelu(mx);
    o[192 + c] = lrelu(mn);
    o[384 + c] = lrelu(sm);
    o[576 + c] = lrelu(sm * (1.0f / 512.0f));
}

// ---------------------------------------------------------------- head
__global__ __launch_bounds__(128)
void head_kernel(const float* __restrict__ pooledL,
                 const float* __restrict__ W3, const float* __restrict__ b3,
                 const float* __restrict__ W4, const float* __restrict__ b4,
                 float* __restrict__ out) {
    __shared__ float pl[768];
    __shared__ float h3[96];
    const int b = blockIdx.x, t = threadIdx.x;
    for (int i = t; i < 768; i += 128) pl[i] = pooledL[(size_t)b * 768 + i];
    __syncthreads();
    if (t < 96) {
        float acc = b3[t];
        for (int k = 0; k < 768; k++) acc += pl[k] * W3[(size_t)k * 96 + t];
        h3[t] = lrelu(acc);
    }
    __syncthreads();
    if (t == 0) {
        float s2 = b4[0];
        for (int o = 0; o < 96; o++) s2 += h3[o] * W4[o];
        out[b] = s2;
    }
}

// ---------------------------------------------------------------- launch
extern "C" void kernel_launch(void* const* d_in, const int* in_sizes, int n_in,
                              void* d_out, int out_size, void* d_ws, size_t ws_size,
                              hipStream_t stream) {
    const float* x    = (const float*)d_in[0];
    const float* c1w1 = (const float*)d_in[1];
    const float* c1b1 = (const float*)d_in[2];
    const float* c1w2 = (const float*)d_in[3];
    const float* c1b2 = (const float*)d_in[4];
    const float* cw1[3] = {(const float*)d_in[5], (const float*)d_in[9],  (const float*)d_in[13]};
    const float* cb1[3] = {(const float*)d_in[6], (const float*)d_in[10], (const float*)d_in[14]};
    const float* cw2[3] = {(const float*)d_in[7], (const float*)d_in[11], (const float*)d_in[15]};
    const float* cb2[3] = {(const float*)d_in[8], (const float*)d_in[12], (const float*)d_in[16]};
    const float* nn1w = (const float*)d_in[17];
    const float* nn1b = (const float*)d_in[18];
    const float* nn2w = (const float*)d_in[19];
    const float* nn2b = (const float*)d_in[20];
    const float* nn3w = (const float*)d_in[21];
    const float* nn3b = (const float*)d_in[22];
    const float* nn4w = (const float*)d_in[23];
    const float* nn4b = (const float*)d_in[24];
    float* out = (float*)d_out;

    // workspace layout (float units)
    const size_t featN  = (size_t)BB * NN * 192;
    const size_t idx_f  = (size_t)BB * NN * KNNK;
    const size_t part_f = (size_t)BB * 8 * 3 * 192;
    const size_t pool_f = (size_t)BB * 768;
    const size_t wcat_f = (size_t)192 * 512;
    const size_t w1t_f  = (size_t)256 * 800 / 2;   // ushort plane in float units
    const size_t n2t_f  = (size_t)192 * 256 / 2;
    const size_t w2p_f  = (size_t)3 * 192 * 256 / 2;

    float* abuf = (float*)d_ws;
    float* bbuf = abuf + featN;
    float* cbuf = bbuf + featN;
    float* dbuf = cbuf + featN;
    int*   idxb = (int*)(dbuf + featN);
    float* partials = (float*)(idxb + idx_f);
    float* pooledL = partials + part_f;
    float* wcat = pooledL + pool_f;
    unsigned short* w1t_hi = (unsigned short*)(wcat + wcat_f);
    unsigned short* w1t_lo = (unsigned short*)(wcat + wcat_f + w1t_f);
    unsigned short* n2t_hi = (unsigned short*)(wcat + wcat_f + 2 * w1t_f);
    unsigned short* n2t_lo = (unsigned short*)(wcat + wcat_f + 2 * w1t_f + n2t_f);
    unsigned short* w2p    = (unsigned short*)(wcat + wcat_f + 2 * w1t_f + 2 * n2t_f);
    float* pqbuf = wcat + wcat_f + 2 * w1t_f + 2 * n2t_f + w2p_f;

    const size_t fixed_f = 4 * featN + idx_f + part_f + pool_f + wcat_f
                         + 2 * w1t_f + 2 * n2t_f + w2p_f;
    int CB = BB;
    while (CB > 1) {
        const size_t need = (fixed_f + (size_t)CB * NN * 512) * 4;
        if (need <= ws_size) break;
        CB >>= 1;
    }
    const int nchunks = BB / CB;

    float* feats[4] = {abuf, bbuf, cbuf, dbuf};

    knn_kernel<<<BB, 512, 0, stream>>>(x, 4, idxb);
    conv1_kernel<<<BB * 32, 256, 0, stream>>>(x, idxb, c1w1, c1b1, c1w2, c1b2, abuf);

    for (int L = 0; L < 3; ++L) {
        const float* fin = feats[L];
        float* fout = feats[L + 1];
        knn_kernel<<<BB, 512, 0, stream>>>(fin, 192, idxb);
        wprep_kernel<<<(192 * 512) / 256, 256, 0, stream>>>(cw1[L], wcat);
        wprep2_kernel<<<(192 * 256) / 256, 256, 0, stream>>>(cw2[L], w2p);
        for (int ch = 0; ch < nchunks; ++ch) {
            const size_t roff = (size_t)ch * CB * NN;
            pq_gemm_kernel<<<CB * 32, 256, 0, stream>>>(fin + roff * 192, wcat, pqbuf);
            conv234e_mfma_kernel<<<CB * 16, 256, 0, stream>>>(pqbuf, idxb + roff * KNNK,
                                                              w2p, cb1[L], cb2[L],
                                                              fout + roff * 192);
        }
    }

    // nn phase (MFMA bf16x3); h1 reuses pqbuf
    nn1prep_kernel<<<(256 * 800) / 256, 256, 0, stream>>>(nn1w, w1t_hi, w1t_lo);
    nn2prep_kernel<<<(192 * 256) / 256, 256, 0, stream>>>(nn2w, n2t_hi, n2t_lo);
    float* h1buf = pqbuf;
    for (int ch = 0; ch < nchunks; ++ch) {
        const size_t roff = (size_t)ch * CB * NN;
        nn1_mfma_kernel<<<CB * 8, 256, 0, stream>>>(x + roff * 4,
                                                    abuf + roff * 192, bbuf + roff * 192,
                                                    cbuf + roff * 192, dbuf + roff * 192,
                                                    w1t_hi, w1t_lo, nn1b, h1buf);
        nn2pool_mfma_kernel<<<CB * 8, 256, 0, stream>>>(h1buf, n2t_hi, n2t_lo, nn2b,
                                                        (int)roff, partials);
    }
    pool_reduce_kernel<<<BB, 192, 0, stream>>>(partials, pooledL);
    head_kernel<<<BB, 128, 0, stream>>>(pooledL, nn3w, nn3b, nn4w, nn4b, out);
}

// Round 7
// 2093.559 us; speedup vs baseline: 1.3598x; 1.1570x over previous
//
#include <hip/hip_runtime.h>

#define BB 128
#define NN 512
#define KNNK 4

typedef __attribute__((ext_vector_type(8))) short s8v;
typedef __attribute__((ext_vector_type(4))) float f4v;

__device__ __forceinline__ float lrelu(float v) { return v > 0.0f ? v : 0.01f * v; }

__device__ __forceinline__ unsigned short f2bf(float f) {
    unsigned int u = __float_as_uint(f);
    u += 0x7FFFu + ((u >> 16) & 1u);   // RTNE
    return (unsigned short)(u >> 16);
}
__device__ __forceinline__ float bf2f(unsigned short s) {
    return __uint_as_float(((unsigned int)s) << 16);
}

// ---------------------------------------------------------------- kNN (original, bit-exact R4)
__global__ __launch_bounds__(512)
void knn_kernel(const float* __restrict__ feat, int ldf, int* __restrict__ idx_out) {
    __shared__ float px[NN], py[NN], pz[NN], sq[NN];
    const int b = blockIdx.x;
    const int i = threadIdx.x;
    const float* fb = feat + (size_t)b * NN * ldf;
    const float x = fb[(size_t)i * ldf + 0];
    const float y = fb[(size_t)i * ldf + 1];
    const float z = fb[(size_t)i * ldf + 2];
    px[i] = x; py[i] = y; pz[i] = z;
    const float s = x * x + y * y + z * z;
    sq[i] = s;
    __syncthreads();
    float bd0 = 3.4e38f, bd1 = 3.4e38f, bd2 = 3.4e38f, bd3 = 3.4e38f;
    int bj0 = 0, bj1 = 0, bj2 = 0, bj3 = 0;
    for (int j = 0; j < NN; j++) {
        const float d2 = s + sq[j] - 2.0f * (x * px[j] + y * py[j] + z * pz[j]);
        if (j != i && d2 < bd3) {
            if (d2 < bd2) {
                bd3 = bd2; bj3 = bj2;
                if (d2 < bd1) {
                    bd2 = bd1; bj2 = bj1;
                    if (d2 < bd0) { bd1 = bd0; bj1 = bj0; bd0 = d2; bj0 = j; }
                    else { bd1 = d2; bj1 = j; }
                } else { bd2 = d2; bj2 = j; }
            } else { bd3 = d2; bj3 = j; }
        }
    }
    int* ip = idx_out + ((size_t)b * NN + i) * KNNK;
    ip[0] = bj0; ip[1] = bj1; ip[2] = bj2; ip[3] = bj3;
}

// ---------------------------------------------------------------- conv1 (R2 fp32 version, bit-exact R4)
__global__ __launch_bounds__(256, 2)
void conv1_kernel(const float* __restrict__ X,
                  const int* __restrict__ nidx,
                  const float* __restrict__ W1, const float* __restrict__ b1,
                  const float* __restrict__ W2, const float* __restrict__ b2,
                  float* __restrict__ out)
{
    __shared__ float E[8][64];
    __shared__ float W1s[8][96];
    __shared__ float h1t[96][64];
    __shared__ float W2t[32][192];
    __shared__ float b1s[96], b2s[192];

    const int t = threadIdx.x;
    const int b = blockIdx.x >> 5;
    const int nb = (blockIdx.x & 31) << 4;
    const float* Xb = X + (size_t)b * NN * 4;

    for (int i = t; i < 8 * 96; i += 256) W1s[i / 96][i % 96] = W1[i];
    if (t < 96) b1s[t] = b1[t];
    if (t < 192) b2s[t] = b2[t];

    if (t < 64) {
        const int e = t;
        const int node = nb + (e >> 2);
        const int j = nidx[((size_t)b * NN + node) * KNNK + (e & 3)];
        const float4 xi = *(const float4*)(Xb + (size_t)node * 4);
        const float4 xj = *(const float4*)(Xb + (size_t)j * 4);
        E[0][e] = xi.x; E[1][e] = xi.y; E[2][e] = xi.z; E[3][e] = xi.w;
        E[4][e] = xj.x - xi.x; E[5][e] = xj.y - xi.y; E[6][e] = xj.z - xi.z; E[7][e] = xj.w - xi.w;
    }
    __syncthreads();

    const int rg = t & 15;
    {   // GEMM1
        const int cg = t >> 4;
        float acc[4][6];
#pragma unroll
        for (int r = 0; r < 4; r++)
#pragma unroll
            for (int c = 0; c < 6; c++) acc[r][c] = 0.0f;
#pragma unroll
        for (int k = 0; k < 8; k++) {
            const float4 e4 = *(const float4*)&E[k][rg * 4];
            const float er[4] = {e4.x, e4.y, e4.z, e4.w};
            float wc[6];
#pragma unroll
            for (int c = 0; c < 6; c++) wc[c] = W1s[k][cg * 6 + c];
#pragma unroll
            for (int r = 0; r < 4; r++)
#pragma unroll
                for (int c = 0; c < 6; c++) acc[r][c] += er[r] * wc[c];
        }
#pragma unroll
        for (int c = 0; c < 6; c++) {
            const int col = cg * 6 + c;
            const float bias = b1s[col];
#pragma unroll
            for (int r = 0; r < 4; r++) h1t[col][rg * 4 + r] = lrelu(acc[r][c] + bias);
        }
    }
    __syncthreads();

    {   // GEMM2
        const int cg = t >> 4;
        float acc[4][12];
#pragma unroll
        for (int r = 0; r < 4; r++)
#pragma unroll
            for (int c = 0; c < 12; c++) acc[r][c] = 0.0f;
        for (int kt = 0; kt < 3; kt++) {
            for (int i = t; i < 32 * 192; i += 256)
                W2t[i / 192][i % 192] = W2[(size_t)(kt * 32 + i / 192) * 192 + i % 192];
            __syncthreads();
#pragma unroll
            for (int kk = 0; kk < 32; kk++) {
                const int k = kt * 32 + kk;
                const float4 e4 = *(const float4*)&h1t[k][rg * 4];
                const float er[4] = {e4.x, e4.y, e4.z, e4.w};
                float wc[12];
#pragma unroll
                for (int c = 0; c < 12; c += 4) {
                    const float4 w4 = *(const float4*)&W2t[kk][cg * 12 + c];
                    wc[c] = w4.x; wc[c + 1] = w4.y; wc[c + 2] = w4.z; wc[c + 3] = w4.w;
                }
#pragma unroll
                for (int r = 0; r < 4; r++)
#pragma unroll
                    for (int c = 0; c < 12; c++) acc[r][c] += er[r] * wc[c];
            }
            __syncthreads();
        }
        const int node = nb + rg;
        float res[12];
#pragma unroll
        for (int c = 0; c < 12; c++) {
            const float bias = b2s[cg * 12 + c];
            res[c] = lrelu(acc[0][c] + bias) + lrelu(acc[1][c] + bias)
                   + lrelu(acc[2][c] + bias) + lrelu(acc[3][c] + bias);
        }
        float* op = out + ((size_t)b * NN + node) * 192 + cg * 12;
#pragma unroll
        for (int c = 0; c < 12; c += 4) {
            float4 o; o.x = res[c]; o.y = res[c + 1]; o.z = res[c + 2]; o.w = res[c + 3];
            *(float4*)(op + c) = o;
        }
    }
}

// ---------------------------------------------------------------- weight prep (fp32 Wcat, layers 2-3)
__global__ void wprep_kernel(const float* __restrict__ W1, float* __restrict__ Wcat) {
    const int idx = blockIdx.x * 256 + threadIdx.x;   // 192*512
    const int k = idx >> 9;
    const int c = idx & 511;
    float v = 0.0f;
    if (c < 252) v = W1[(size_t)k * 252 + c] - W1[(size_t)(192 + k) * 252 + c];
    else if (c >= 256 && c < 508) v = W1[(size_t)(192 + k) * 252 + (c - 256)];
    Wcat[idx] = v;
}

// conv W1 -> Wcat 3 bf16 planes [512 col][192 k] (layer 4 only)
__global__ void wprep3_kernel(const float* __restrict__ W1, unsigned short* __restrict__ wcat3) {
    const int idx = blockIdx.x * 256 + threadIdx.x;   // 512*192
    const int c = idx / 192, k = idx % 192;
    float v = 0.0f;
    if (c < 252) v = W1[(size_t)k * 252 + c] - W1[(size_t)(192 + k) * 252 + c];
    else if (c >= 256 && c < 508) v = W1[(size_t)(192 + k) * 252 + (c - 256)];
    const unsigned short c0 = f2bf(v);
    const float r1 = v - bf2f(c0);
    const unsigned short c1 = f2bf(r1);
    const float r2 = r1 - bf2f(c1);
    wcat3[idx] = c0;
    wcat3[98304 + idx] = c1;
    wcat3[196608 + idx] = f2bf(r2);
}

// conv W2 -> 3 bf16 planes [192][256] (for conve)
__global__ void wprep2_kernel(const float* __restrict__ W2, unsigned short* __restrict__ w2p) {
    const int idx = blockIdx.x * 256 + threadIdx.x;  // 192*256
    const int col = idx >> 8, k = idx & 255;
    const float v = (k < 252) ? W2[(size_t)k * 192 + col] : 0.0f;
    const unsigned short c0 = f2bf(v);
    const float r1 = v - bf2f(c0);
    const unsigned short c1 = f2bf(r1);
    const float r2 = r1 - bf2f(c1);
    w2p[idx] = c0;
    w2p[49152 + idx] = c1;
    w2p[98304 + idx] = f2bf(r2);
}

// ---------------------------------------------------------------- PQ node GEMM (fp32, layers 2-3: feeds kNN cone, bit-exact R4)
__global__ __launch_bounds__(256, 4)
void pq_gemm_kernel(const float* __restrict__ X,
                    const float* __restrict__ Wcat,
                    float* __restrict__ PQ)
{
    __shared__ float Xt[16][68];
    __shared__ float Wt[16][128];
    const int t = threadIdx.x;
    const int m0 = (blockIdx.x >> 2) << 6;
    const int n0 = (blockIdx.x & 3) << 7;

    const int rg = t & 15, cg = t >> 4;
    const int sm = t >> 2;
    const int skq = (t & 3) << 2;

    const int q0 = t, q1 = t + 256;
    const int kkA = q0 >> 5, c4A = (q0 & 31) << 2;
    const int kkB = q1 >> 5, c4B = (q1 & 31) << 2;

    float acc[4][8];
#pragma unroll
    for (int r = 0; r < 4; r++)
#pragma unroll
        for (int c = 0; c < 8; c++) acc[r][c] = 0.0f;

    for (int kt = 0; kt < 12; ++kt) {
        const int k0 = kt << 4;
        const float4 xv = *(const float4*)&X[(size_t)(m0 + sm) * 192 + k0 + skq];
        Xt[skq + 0][sm] = xv.x;
        Xt[skq + 1][sm] = xv.y;
        Xt[skq + 2][sm] = xv.z;
        Xt[skq + 3][sm] = xv.w;
        *(float4*)&Wt[kkA][c4A] = *(const float4*)&Wcat[(size_t)(k0 + kkA) * 512 + n0 + c4A];
        *(float4*)&Wt[kkB][c4B] = *(const float4*)&Wcat[(size_t)(k0 + kkB) * 512 + n0 + c4B];
        __syncthreads();
#pragma unroll
        for (int kk = 0; kk < 16; ++kk) {
            const float4 x4 = *(const float4*)&Xt[kk][rg * 4];
            const float4 w0 = *(const float4*)&Wt[kk][cg * 8];
            const float4 w1 = *(const float4*)&Wt[kk][cg * 8 + 4];
            const float xr[4] = {x4.x, x4.y, x4.z, x4.w};
            const float wc[8] = {w0.x, w0.y, w0.z, w0.w, w1.x, w1.y, w1.z, w1.w};
#pragma unroll
            for (int r = 0; r < 4; r++)
#pragma unroll
                for (int c = 0; c < 8; c++) acc[r][c] += xr[r] * wc[c];
        }
        __syncthreads();
    }
#pragma unroll
    for (int r = 0; r < 4; r++) {
        float* op = PQ + (size_t)(m0 + rg * 4 + r) * 512 + n0 + cg * 8;
        float4 o0; o0.x = acc[r][0]; o0.y = acc[r][1]; o0.z = acc[r][2]; o0.w = acc[r][3];
        float4 o1; o1.x = acc[r][4]; o1.y = acc[r][5]; o1.z = acc[r][6]; o1.w = acc[r][7];
        *(float4*)op = o0;
        *(float4*)(op + 4) = o1;
    }
}

// ---------------------------------------------------------------- PQ node GEMM bf16x6 MFMA (layer 4 only: no kNN downstream)
__global__ __launch_bounds__(256, 3)
void pq_mfma_kernel(const float* __restrict__ X,
                    const unsigned short* __restrict__ wcat3,  // 3 planes [512][192]
                    float* __restrict__ PQ)
{
    __shared__ float Xt[32][66];
    __shared__ unsigned short Bl[3][128][32];

    const int t = threadIdx.x;
    const int m0 = (blockIdx.x >> 2) << 6;
    const int n0 = (blockIdx.x & 3) << 7;
    const int wv = t >> 6, l = t & 63, lm = l & 15, g = l >> 4;
    const int srow = t >> 2, skq = (t & 3) << 3;

    f4v acc[8];
#pragma unroll
    for (int i = 0; i < 8; i++) acc[i] = (f4v){0.0f, 0.0f, 0.0f, 0.0f};

    for (int kt = 0; kt < 6; ++kt) {
        const int k0 = kt << 5;
        {   // stage X fp32
            const float* sp = &X[(size_t)(m0 + srow) * 192 + k0 + skq];
            const float4 xa = *(const float4*)sp;
            const float4 xb = *(const float4*)(sp + 4);
            Xt[skq + 0][srow] = xa.x; Xt[skq + 1][srow] = xa.y;
            Xt[skq + 2][srow] = xa.z; Xt[skq + 3][srow] = xa.w;
            Xt[skq + 4][srow] = xb.x; Xt[skq + 5][srow] = xb.y;
            Xt[skq + 6][srow] = xb.z; Xt[skq + 7][srow] = xb.w;
        }
#pragma unroll
        for (int it = 0; it < 6; ++it) {   // stage B: 3 planes x 128 cols x 4 chunks
            const int p = it >> 1;
            const int col = (it & 1) * 64 + (t >> 2);
            const int chunk = t & 3;
            const int pos = chunk ^ ((col >> 1) & 3);
            *(s8v*)&Bl[p][col][pos * 8] =
                *(const s8v*)&wcat3[(size_t)p * 98304 + (size_t)(n0 + col) * 192 + k0 + chunk * 8];
        }
        __syncthreads();

        s8v A0, A1, A2;
#pragma unroll
        for (int i = 0; i < 8; ++i) {
            const float hv = Xt[g * 8 + i][wv * 16 + lm];
            const unsigned short c0 = f2bf(hv);
            const float r1 = hv - bf2f(c0);
            const unsigned short c1 = f2bf(r1);
            const float r2 = r1 - bf2f(c1);
            A0[i] = (short)c0;
            A1[i] = (short)c1;
            A2[i] = (short)f2bf(r2);
        }
#pragma unroll
        for (int nt = 0; nt < 8; ++nt) {
            const int col = nt * 16 + lm;
            const int pos = g ^ ((col >> 1) & 3);
            const s8v B0 = *(const s8v*)&Bl[0][col][pos * 8];
            const s8v B1 = *(const s8v*)&Bl[1][col][pos * 8];
            const s8v B2 = *(const s8v*)&Bl[2][col][pos * 8];
            acc[nt] = __builtin_amdgcn_mfma_f32_16x16x32_bf16(A0, B0, acc[nt], 0, 0, 0);
            acc[nt] = __builtin_amdgcn_mfma_f32_16x16x32_bf16(A0, B1, acc[nt], 0, 0, 0);
            acc[nt] = __builtin_amdgcn_mfma_f32_16x16x32_bf16(A1, B0, acc[nt], 0, 0, 0);
            acc[nt] = __builtin_amdgcn_mfma_f32_16x16x32_bf16(A1, B1, acc[nt], 0, 0, 0);
            acc[nt] = __builtin_amdgcn_mfma_f32_16x16x32_bf16(A0, B2, acc[nt], 0, 0, 0);
            acc[nt] = __builtin_amdgcn_mfma_f32_16x16x32_bf16(A2, B0, acc[nt], 0, 0, 0);
        }
        __syncthreads();
    }
#pragma unroll
    for (int nt = 0; nt < 8; ++nt) {
        const int col = n0 + nt * 16 + lm;
#pragma unroll
        for (int r = 0; r < 4; ++r) {
            PQ[(size_t)(m0 + wv * 16 + g * 4 + r) * 512 + col] = acc[nt][r];
        }
    }
}

// ---------------------------------------------------------------- conv2/3/4 edge phase: bf16x6 MFMA (bit-exact R4)
__global__ __launch_bounds__(256, 2)
void conv234e_mfma_kernel(const float* __restrict__ PQ,
                          const int* __restrict__ nidx,
                          const unsigned short* __restrict__ w2p,  // 3 planes [192][256]
                          const float* __restrict__ b1,
                          const float* __restrict__ b2,
                          float* __restrict__ out)
{
    __shared__ float h1c[32][132];
    __shared__ unsigned short Bl[3][192][32];
    __shared__ float b1s[256];
    __shared__ float b2s[192];

    const int t = threadIdx.x;
    const int nodebase = (blockIdx.x >> 4) << 9;
    const int nb = (blockIdx.x & 15) << 5;

    b1s[t] = (t < 252) ? b1[t] : 0.0f;
    if (t < 192) b2s[t] = b2[t];

    const int m = t >> 3, s = t & 7;
    const int4 jj = *(const int4*)&nidx[(size_t)(nodebase + nb + m) * 4];
    const float* Prow = PQ + (size_t)(nodebase + nb + m) * 512;
    const float* Q0 = PQ + (size_t)(nodebase + jj.x) * 512 + 256;
    const float* Q1 = PQ + (size_t)(nodebase + jj.y) * 512 + 256;
    const float* Q2 = PQ + (size_t)(nodebase + jj.z) * 512 + 256;
    const float* Q3 = PQ + (size_t)(nodebase + jj.w) * 512 + 256;

    const int bcol = t >> 2, bchk = t & 3;
    const int w = t >> 6, l = t & 63, lm = l & 15, g = l >> 4;
    const int mhalf = w & 1, nhalf = w >> 1;

    f4v acc[4][6];
#pragma unroll
    for (int i = 0; i < 4; i++)
#pragma unroll
        for (int j = 0; j < 6; j++) acc[i][j] = (f4v){0.0f, 0.0f, 0.0f, 0.0f};

    __syncthreads();

    for (int kt = 0; kt < 8; ++kt) {
        const int k0 = kt << 5;
        {   // stage A: h1 fp32, 4 k x 4 edges per thread
            const int kq = s << 2;
            const float4 pv = *(const float4*)&Prow[k0 + kq];
            const float4 bb = *(const float4*)&b1s[k0 + kq];
            const float4 qa = *(const float4*)&Q0[k0 + kq];
            const float4 qb = *(const float4*)&Q1[k0 + kq];
            const float4 qc = *(const float4*)&Q2[k0 + kq];
            const float4 qd = *(const float4*)&Q3[k0 + kq];
            const float p0 = pv.x + bb.x, p1 = pv.y + bb.y, p2 = pv.z + bb.z, p3 = pv.w + bb.w;
            float4 h;
            h.x = lrelu(p0 + qa.x); h.y = lrelu(p0 + qb.x); h.z = lrelu(p0 + qc.x); h.w = lrelu(p0 + qd.x);
            *(float4*)&h1c[kq + 0][m * 4] = h;
            h.x = lrelu(p1 + qa.y); h.y = lrelu(p1 + qb.y); h.z = lrelu(p1 + qc.y); h.w = lrelu(p1 + qd.y);
            *(float4*)&h1c[kq + 1][m * 4] = h;
            h.x = lrelu(p2 + qa.z); h.y = lrelu(p2 + qb.z); h.z = lrelu(p2 + qc.z); h.w = lrelu(p2 + qd.z);
            *(float4*)&h1c[kq + 2][m * 4] = h;
            h.x = lrelu(p3 + qa.w); h.y = lrelu(p3 + qb.w); h.z = lrelu(p3 + qc.w); h.w = lrelu(p3 + qd.w);
            *(float4*)&h1c[kq + 3][m * 4] = h;
        }
#pragma unroll
        for (int it = 0; it < 9; ++it) {
            const int p = it / 3;
            const int col = (it % 3) * 64 + bcol;
            const int pos = bchk ^ ((col >> 1) & 3);
            *(s8v*)&Bl[p][col][pos * 8] =
                *(const s8v*)&w2p[(size_t)p * 49152 + (size_t)col * 256 + k0 + bchk * 8];
        }
        __syncthreads();

        s8v A0[4], A1[4], A2[4];
#pragma unroll
        for (int mt = 0; mt < 4; ++mt) {
            const int edge = mhalf * 64 + mt * 16 + lm;
#pragma unroll
            for (int i = 0; i < 8; ++i) {
                const float hv = h1c[g * 8 + i][edge];
                const unsigned short c0 = f2bf(hv);
                const float r1 = hv - bf2f(c0);
                const unsigned short c1 = f2bf(r1);
                const float r2 = r1 - bf2f(c1);
                A0[mt][i] = (short)c0;
                A1[mt][i] = (short)c1;
                A2[mt][i] = (short)f2bf(r2);
            }
        }
#pragma unroll
        for (int nt = 0; nt < 6; ++nt) {
            const int col = nhalf * 96 + nt * 16 + lm;
            const int pos = g ^ ((col >> 1) & 3);
            const s8v B0 = *(const s8v*)&Bl[0][col][pos * 8];
            const s8v B1 = *(const s8v*)&Bl[1][col][pos * 8];
            const s8v B2 = *(const s8v*)&Bl[2][col][pos * 8];
#pragma unroll
            for (int mt = 0; mt < 4; ++mt) {
                acc[mt][nt] = __builtin_amdgcn_mfma_f32_16x16x32_bf16(A0[mt], B0, acc[mt][nt], 0, 0, 0);
                acc[mt][nt] = __builtin_amdgcn_mfma_f32_16x16x32_bf16(A0[mt], B1, acc[mt][nt], 0, 0, 0);
                acc[mt][nt] = __builtin_amdgcn_mfma_f32_16x16x32_bf16(A1[mt], B0, acc[mt][nt], 0, 0, 0);
                acc[mt][nt] = __builtin_amdgcn_mfma_f32_16x16x32_bf16(A1[mt], B1, acc[mt][nt], 0, 0, 0);
                acc[mt][nt] = __builtin_amdgcn_mfma_f32_16x16x32_bf16(A0[mt], B2, acc[mt][nt], 0, 0, 0);
                acc[mt][nt] = __builtin_amdgcn_mfma_f32_16x16x32_bf16(A2[mt], B0, acc[mt][nt], 0, 0, 0);
            }
        }
        __syncthreads();
    }

#pragma unroll
    for (int mt = 0; mt < 4; ++mt) {
        const int node = nodebase + nb + mhalf * 16 + mt * 4 + g;
#pragma unroll
        for (int nt = 0; nt < 6; ++nt) {
            const int col = nhalf * 96 + nt * 16 + lm;
            const float bias = b2s[col];
            const f4v v = acc[mt][nt];
            out[(size_t)node * 192 + col] =
                lrelu(v[0] + bias) + lrelu(v[1] + bias) + lrelu(v[2] + bias) + lrelu(v[3] + bias);
        }
    }
}

// ---------------------------------------------------------------- nn weight preps
__global__ void nn1prep_kernel(const float* __restrict__ W1,
                               unsigned short* __restrict__ hi,
                               unsigned short* __restrict__ lo) {
    const int idx = blockIdx.x * 256 + threadIdx.x;  // 256*800
    const int col = idx / 800, k = idx % 800;
    float v = 0.0f;
    if (col < 252) {
        if (k < 4) v = W1[(size_t)k * 252 + col];
        else if (k >= 32) {
            const int s = (k - 32) / 192, kk = (k - 32) % 192;
            v = W1[(size_t)(4 + s * 192 + kk) * 252 + col];
        }
    }
    const unsigned short h = f2bf(v);
    hi[idx] = h;
    lo[idx] = f2bf(v - bf2f(h));
}

__global__ void nn2prep_kernel(const float* __restrict__ W2,
                               unsigned short* __restrict__ hi,
                               unsigned short* __restrict__ lo) {
    const int idx = blockIdx.x * 256 + threadIdx.x;  // 192*256
    const int col = idx >> 8, k = idx & 255;
    const float v = (k < 252) ? W2[(size_t)k * 192 + col] : 0.0f;
    const unsigned short h = f2bf(v);
    hi[idx] = h;
    lo[idx] = f2bf(v - bf2f(h));
}

// ---------------------------------------------------------------- nn1 MFMA (bf16x3) + LDS B staging
__global__ __launch_bounds__(256)
void nn1_mfma_kernel(const float* __restrict__ x,
                     const float* __restrict__ a,
                     const float* __restrict__ bf,
                     const float* __restrict__ cf,
                     const float* __restrict__ df,
                     const unsigned short* __restrict__ w1t_hi,
                     const unsigned short* __restrict__ w1t_lo,
                     const float* __restrict__ b1,
                     float* __restrict__ h1)
{
    __shared__ unsigned short Bl[2][256][32];
    const int t = threadIdx.x;
    const int wv = t >> 6, l = t & 63, lm = l & 15, g = l >> 4;
    const int m0 = blockIdx.x << 6;
    const int row = m0 + wv * 16 + lm;
    const int scol = t >> 2, schunk = t & 3;

    f4v acc[16];
#pragma unroll
    for (int i = 0; i < 16; i++) acc[i] = (f4v){0.0f, 0.0f, 0.0f, 0.0f};

    const float* segp[4] = {a, bf, cf, df};

#pragma unroll 1
    for (int step = 0; step < 25; ++step) {
        const int kb0 = step * 32;
        {   // stage B: 2 planes x 256 cols x 4 chunks (8 x 16B per thread)
#pragma unroll
            for (int it = 0; it < 8; ++it) {
                const int p = it >> 2;
                const int col = (it & 3) * 64 + scol;
                const int pos = schunk ^ ((col >> 1) & 3);
                const unsigned short* src = (p == 0) ? w1t_hi : w1t_lo;
                *(s8v*)&Bl[p][col][pos * 8] =
                    *(const s8v*)&src[(size_t)col * 800 + kb0 + schunk * 8];
            }
        }
        float v[8];
        if (step == 0) {
            if (g == 0) {
                const float4 xv = *(const float4*)&x[(size_t)row * 4];
                v[0] = xv.x; v[1] = xv.y; v[2] = xv.z; v[3] = xv.w;
                v[4] = v[5] = v[6] = v[7] = 0.0f;
            } else {
#pragma unroll
                for (int i = 0; i < 8; i++) v[i] = 0.0f;
            }
        } else {
            const int s = (step - 1) / 6;
            const int kin = ((step - 1) % 6) * 32 + g * 8;
            const float* sp = segp[s] + (size_t)row * 192 + kin;
            const float4 a0 = *(const float4*)sp;
            const float4 a1 = *(const float4*)(sp + 4);
            v[0] = a0.x; v[1] = a0.y; v[2] = a0.z; v[3] = a0.w;
            v[4] = a1.x; v[5] = a1.y; v[6] = a1.z; v[7] = a1.w;
        }
        s8v ahi, alo;
#pragma unroll
        for (int i = 0; i < 8; i++) {
            const unsigned short h = f2bf(v[i]);
            ahi[i] = (short)h;
            alo[i] = (short)f2bf(v[i] - bf2f(h));
        }
        __syncthreads();
#pragma unroll
        for (int nt = 0; nt < 16; ++nt) {
            const int col = nt * 16 + lm;
            const int pos = g ^ ((col >> 1) & 3);
            const s8v bhi = *(const s8v*)&Bl[0][col][pos * 8];
            const s8v blo = *(const s8v*)&Bl[1][col][pos * 8];
            acc[nt] = __builtin_amdgcn_mfma_f32_16x16x32_bf16(ahi, bhi, acc[nt], 0, 0, 0);
            acc[nt] = __builtin_amdgcn_mfma_f32_16x16x32_bf16(ahi, blo, acc[nt], 0, 0, 0);
            acc[nt] = __builtin_amdgcn_mfma_f32_16x16x32_bf16(alo, bhi, acc[nt], 0, 0, 0);
        }
        __syncthreads();
    }
#pragma unroll
    for (int nt = 0; nt < 16; ++nt) {
        const int col = nt * 16 + lm;
        const float bias = (col < 252) ? b1[col] : 0.0f;
#pragma unroll
        for (int r = 0; r < 4; ++r) {
            const int orow = m0 + wv * 16 + g * 4 + r;
            h1[(size_t)orow * 256 + col] = lrelu(acc[nt][r] + bias);
        }
    }
}

// ---------------------------------------------------------------- nn2 MFMA + fused pooling + LDS B staging
__global__ __launch_bounds__(256)
void nn2pool_mfma_kernel(const float* __restrict__ h1,
                         const unsigned short* __restrict__ n2t_hi,
                         const unsigned short* __restrict__ n2t_lo,
                         const float* __restrict__ b2,
                         int grow0,
                         float* __restrict__ partials)
{
    __shared__ unsigned short Bl[2][192][32];
    __shared__ float red[4][3][192];
    const int t = threadIdx.x;
    const int wv = t >> 6, l = t & 63, lm = l & 15, g = l >> 4;
    const int m0 = blockIdx.x << 6;
    const int row = m0 + wv * 16 + lm;
    const int scol = t >> 2, schunk = t & 3;

    f4v acc[12];
#pragma unroll
    for (int i = 0; i < 12; i++) acc[i] = (f4v){0.0f, 0.0f, 0.0f, 0.0f};

#pragma unroll 1
    for (int step = 0; step < 8; ++step) {
        const int kb0 = step * 32;
        {   // stage B: 2 planes x 192 cols x 4 chunks (6 x 16B per thread)
#pragma unroll
            for (int it = 0; it < 6; ++it) {
                const int p = it / 3;
                const int col = (it % 3) * 64 + scol;
                const int pos = schunk ^ ((col >> 1) & 3);
                const unsigned short* src = (p == 0) ? n2t_hi : n2t_lo;
                *(s8v*)&Bl[p][col][pos * 8] =
                    *(const s8v*)&src[(size_t)col * 256 + kb0 + schunk * 8];
            }
        }
        const float* sp = h1 + (size_t)row * 256 + kb0 + g * 8;
        const float4 a0 = *(const float4*)sp;
        const float4 a1 = *(const float4*)(sp + 4);
        const float v[8] = {a0.x, a0.y, a0.z, a0.w, a1.x, a1.y, a1.z, a1.w};
        s8v ahi, alo;
#pragma unroll
        for (int i = 0; i < 8; i++) {
            const unsigned short h = f2bf(v[i]);
            ahi[i] = (short)h;
            alo[i] = (short)f2bf(v[i] - bf2f(h));
        }
        __syncthreads();
#pragma unroll
        for (int nt = 0; nt < 12; ++nt) {
            const int col = nt * 16 + lm;
            const int pos = g ^ ((col >> 1) & 3);
            const s8v bhi = *(const s8v*)&Bl[0][col][pos * 8];
            const s8v blo = *(const s8v*)&Bl[1][col][pos * 8];
            acc[nt] = __builtin_amdgcn_mfma_f32_16x16x32_bf16(ahi, bhi, acc[nt], 0, 0, 0);
            acc[nt] = __builtin_amdgcn_mfma_f32_16x16x32_bf16(ahi, blo, acc[nt], 0, 0, 0);
            acc[nt] = __builtin_amdgcn_mfma_f32_16x16x32_bf16(alo, bhi, acc[nt], 0, 0, 0);
        }
        __syncthreads();
    }

    float mx[12], mn[12], sm[12];
#pragma unroll
    for (int nt = 0; nt < 12; ++nt) {
        const float bias = b2[nt * 16 + lm];
        const float v0 = acc[nt][0] + bias, v1 = acc[nt][1] + bias;
        const float v2 = acc[nt][2] + bias, v3 = acc[nt][3] + bias;
        mx[nt] = fmaxf(fmaxf(v0, v1), fmaxf(v2, v3));
        mn[nt] = fminf(fminf(v0, v1), fminf(v2, v3));
        sm[nt] = (v0 + v1) + (v2 + v3);
    }
#pragma unroll
    for (int nt = 0; nt < 12; ++nt) {
        mx[nt] = fmaxf(mx[nt], __shfl_xor(mx[nt], 16));
        mn[nt] = fminf(mn[nt], __shfl_xor(mn[nt], 16));
        sm[nt] += __shfl_xor(sm[nt], 16);
        mx[nt] = fmaxf(mx[nt], __shfl_xor(mx[nt], 32));
        mn[nt] = fminf(mn[nt], __shfl_xor(mn[nt], 32));
        sm[nt] += __shfl_xor(sm[nt], 32);
    }
    if (l < 16) {
#pragma unroll
        for (int nt = 0; nt < 12; ++nt) {
            const int col = nt * 16 + lm;
            red[wv][0][col] = mx[nt];
            red[wv][1][col] = mn[nt];
            red[wv][2][col] = sm[nt];
        }
    }
    __syncthreads();
    if (t < 192) {
        const int grow = grow0 + m0;
        float* pp = partials + (((size_t)(grow >> 9) * 8 + ((grow >> 6) & 7)) * 3) * 192;
        pp[t]       = fmaxf(fmaxf(red[0][0][t], red[1][0][t]), fmaxf(red[2][0][t], red[3][0][t]));
        pp[192 + t] = fminf(fminf(red[0][1][t], red[1][1][t]), fminf(red[2][1][t], red[3][1][t]));
        pp[384 + t] = (red[0][2][t] + red[1][2][t]) + (red[2][2][t] + red[3][2][t]);
    }
}

// ---------------------------------------------------------------- pool reduce + head
__global__ void pool_reduce_kernel(const float* __restrict__ partials, float* __restrict__ pooledL) {
    const int b = blockIdx.x, c = threadIdx.x;
    float mx = -3.4e38f, mn = 3.4e38f, sm = 0.0f;
    for (int blk = 0; blk < 8; blk++) {
        const float* pp = partials + ((size_t)b * 8 + blk) * 3 * 192;
        mx = fmaxf(mx, pp[c]);
        mn = fminf(mn, pp[192 + c]);
        sm += pp[384 + c];
    }
    float* o = pooledL + (size_t)b * 768;
    o[c] = lrelu(mx);
    o[192 + c] = lrelu(mn);
    o[384 + c] = lrelu(sm);
    o[576 + c] = lrelu(sm * (1.0f / 512.0f));
}

__global__ __launch_bounds__(128)
void head_kernel(const float* __restrict__ pooledL,
                 const float* __restrict__ W3, const float* __restrict__ b3,
                 const float* __restrict__ W4, const float* __restrict__ b4,
                 float* __restrict__ out) {
    __shared__ float pl[768];
    __shared__ float h3[96];
    const int b = blockIdx.x, t = threadIdx.x;
    for (int i = t; i < 768; i += 128) pl[i] = pooledL[(size_t)b * 768 + i];
    __syncthreads();
    if (t < 96) {
        float acc = b3[t];
        for (int k = 0; k < 768; k++) acc += pl[k] * W3[(size_t)k * 96 + t];
        h3[t] = lrelu(acc);
    }
    __syncthreads();
    if (t == 0) {
        float s2 = b4[0];
        for (int o = 0; o < 96; o++) s2 += h3[o] * W4[o];
        out[b] = s2;
    }
}

// ---------------------------------------------------------------- launch
extern "C" void kernel_launch(void* const* d_in, const int* in_sizes, int n_in,
                              void* d_out, int out_size, void* d_ws, size_t ws_size,
                              hipStream_t stream) {
    const float* x    = (const float*)d_in[0];
    const float* c1w1 = (const float*)d_in[1];
    const float* c1b1 = (const float*)d_in[2];
    const float* c1w2 = (const float*)d_in[3];
    const float* c1b2 = (const float*)d_in[4];
    const float* cw1[3] = {(const float*)d_in[5], (const float*)d_in[9],  (const float*)d_in[13]};
    const float* cb1[3] = {(const float*)d_in[6], (const float*)d_in[10], (const float*)d_in[14]};
    const float* cw2[3] = {(const float*)d_in[7], (const float*)d_in[11], (const float*)d_in[15]};
    const float* cb2[3] = {(const float*)d_in[8], (const float*)d_in[12], (const float*)d_in[16]};
    const float* nn1w = (const float*)d_in[17];
    const float* nn1b = (const float*)d_in[18];
    const float* nn2w = (const float*)d_in[19];
    const float* nn2b = (const float*)d_in[20];
    const float* nn3w = (const float*)d_in[21];
    const float* nn3b = (const float*)d_in[22];
    const float* nn4w = (const float*)d_in[23];
    const float* nn4b = (const float*)d_in[24];
    float* out = (float*)d_out;

    // workspace layout (float units)
    const size_t featN  = (size_t)BB * NN * 192;
    const size_t idx_f  = (size_t)BB * NN * KNNK;
    const size_t part_f = (size_t)BB * 8 * 3 * 192;
    const size_t pool_f = (size_t)BB * 768;
    const size_t wcat_f = (size_t)192 * 512;
    const size_t w1t_f   = (size_t)256 * 800 / 2;    // ushort plane in float units
    const size_t n2t_f   = (size_t)192 * 256 / 2;
    const size_t w2p_f   = (size_t)3 * 192 * 256 / 2;
    const size_t wcat3_f = (size_t)3 * 512 * 192 / 2;

    float* abuf = (float*)d_ws;
    float* bbuf = abuf + featN;
    float* cbuf = bbuf + featN;
    float* dbuf = cbuf + featN;
    int*   idxb = (int*)(dbuf + featN);
    float* partials = (float*)(idxb + idx_f);
    float* pooledL = partials + part_f;
    float* wcat = pooledL + pool_f;
    float* base = wcat + wcat_f;
    unsigned short* w1t_hi = (unsigned short*)base;
    unsigned short* w1t_lo = (unsigned short*)(base + w1t_f);
    unsigned short* n2t_hi = (unsigned short*)(base + 2 * w1t_f);
    unsigned short* n2t_lo = (unsigned short*)(base + 2 * w1t_f + n2t_f);
    unsigned short* w2p    = (unsigned short*)(base + 2 * w1t_f + 2 * n2t_f);
    unsigned short* wcat3  = (unsigned short*)(base + 2 * w1t_f + 2 * n2t_f + w2p_f);
    float* pqbuf = base + 2 * w1t_f + 2 * n2t_f + w2p_f + wcat3_f;

    const size_t fixed_f = 4 * featN + idx_f + part_f + pool_f + wcat_f
                         + 2 * w1t_f + 2 * n2t_f + w2p_f + wcat3_f;
    int CB = BB;
    while (CB > 1) {
        const size_t need = (fixed_f + (size_t)CB * NN * 512) * 4;
        if (need <= ws_size) break;
        CB >>= 1;
    }
    const int nchunks = BB / CB;

    float* feats[4] = {abuf, bbuf, cbuf, dbuf};

    knn_kernel<<<BB, 512, 0, stream>>>(x, 4, idxb);
    conv1_kernel<<<BB * 32, 256, 0, stream>>>(x, idxb, c1w1, c1b1, c1w2, c1b2, abuf);

    for (int L = 0; L < 3; ++L) {
        const float* fin = feats[L];
        float* fout = feats[L + 1];
        knn_kernel<<<BB, 512, 0, stream>>>(fin, 192, idxb);
        if (L < 2) {
            wprep_kernel<<<(192 * 512) / 256, 256, 0, stream>>>(cw1[L], wcat);
        } else {
            wprep3_kernel<<<(512 * 192) / 256, 256, 0, stream>>>(cw1[L], wcat3);
        }
        wprep2_kernel<<<(192 * 256) / 256, 256, 0, stream>>>(cw2[L], w2p);
        for (int ch = 0; ch < nchunks; ++ch) {
            const size_t roff = (size_t)ch * CB * NN;
            if (L < 2) {
                pq_gemm_kernel<<<CB * 32, 256, 0, stream>>>(fin + roff * 192, wcat, pqbuf);
            } else {
                pq_mfma_kernel<<<CB * 32, 256, 0, stream>>>(fin + roff * 192, wcat3, pqbuf);
            }
            conv234e_mfma_kernel<<<CB * 16, 256, 0, stream>>>(pqbuf, idxb + roff * KNNK,
                                                              w2p, cb1[L], cb2[L],
                                                              fout + roff * 192);
        }
    }

    // nn phase (MFMA bf16x3 + LDS B staging); h1 reuses pqbuf
    nn1prep_kernel<<<(256 * 800) / 256, 256, 0, stream>>>(nn1w, w1t_hi, w1t_lo);
    nn2prep_kernel<<<(192 * 256) / 256, 256, 0, stream>>>(nn2w, n2t_hi, n2t_lo);
    float* h1buf = pqbuf;
    for (int ch = 0; ch < nchunks; ++ch) {
        const size_t roff = (size_t)ch * CB * NN;
        nn1_mfma_kernel<<<CB * 8, 256, 0, stream>>>(x + roff * 4,
                                                    abuf + roff * 192, bbuf + roff * 192,
                                                    cbuf + roff * 192, dbuf + roff * 192,
                                                    w1t_hi, w1t_lo, nn1b, h1buf);
        nn2pool_mfma_kernel<<<CB * 8, 256, 0, stream>>>(h1buf, n2t_hi, n2t_lo, nn2b,
                                                        (int)roff, partials);
    }
    pool_reduce_kernel<<<BB, 192, 0, stream>>>(partials, pooledL);
    head_kernel<<<BB, 128, 0, stream>>>(pooledL, nn3w, nn3b, nn4w, nn4b, out);
}

// Round 8
// 1870.986 us; speedup vs baseline: 1.5216x; 1.1190x over previous
//
#include <hip/hip_runtime.h>

#define BB 128
#define NN 512
#define KNNK 4

typedef __attribute__((ext_vector_type(8))) short s8v;
typedef __attribute__((ext_vector_type(4))) float f4v;

__device__ __forceinline__ float lrelu(float v) { return v > 0.0f ? v : 0.01f * v; }

__device__ __forceinline__ unsigned short f2bf(float f) {
    unsigned int u = __float_as_uint(f);
    u += 0x7FFFu + ((u >> 16) & 1u);   // RTNE
    return (unsigned short)(u >> 16);
}
__device__ __forceinline__ float bf2f(unsigned short s) {
    return __uint_as_float(((unsigned int)s) << 16);
}

// ---------------------------------------------------------------- kNN (original, bit-exact)
__global__ __launch_bounds__(512)
void knn_kernel(const float* __restrict__ feat, int ldf, int* __restrict__ idx_out) {
    __shared__ float px[NN], py[NN], pz[NN], sq[NN];
    const int b = blockIdx.x;
    const int i = threadIdx.x;
    const float* fb = feat + (size_t)b * NN * ldf;
    const float x = fb[(size_t)i * ldf + 0];
    const float y = fb[(size_t)i * ldf + 1];
    const float z = fb[(size_t)i * ldf + 2];
    px[i] = x; py[i] = y; pz[i] = z;
    const float s = x * x + y * y + z * z;
    sq[i] = s;
    __syncthreads();
    float bd0 = 3.4e38f, bd1 = 3.4e38f, bd2 = 3.4e38f, bd3 = 3.4e38f;
    int bj0 = 0, bj1 = 0, bj2 = 0, bj3 = 0;
    for (int j = 0; j < NN; j++) {
        const float d2 = s + sq[j] - 2.0f * (x * px[j] + y * py[j] + z * pz[j]);
        if (j != i && d2 < bd3) {
            if (d2 < bd2) {
                bd3 = bd2; bj3 = bj2;
                if (d2 < bd1) {
                    bd2 = bd1; bj2 = bj1;
                    if (d2 < bd0) { bd1 = bd0; bj1 = bj0; bd0 = d2; bj0 = j; }
                    else { bd1 = d2; bj1 = j; }
                } else { bd2 = d2; bj2 = j; }
            } else { bd3 = d2; bj3 = j; }
        }
    }
    int* ip = idx_out + ((size_t)b * NN + i) * KNNK;
    ip[0] = bj0; ip[1] = bj1; ip[2] = bj2; ip[3] = bj3;
}

// ---------------------------------------------------------------- conv1 (R2 fp32 version, bit-exact)
__global__ __launch_bounds__(256, 2)
void conv1_kernel(const float* __restrict__ X,
                  const int* __restrict__ nidx,
                  const float* __restrict__ W1, const float* __restrict__ b1,
                  const float* __restrict__ W2, const float* __restrict__ b2,
                  float* __restrict__ out)
{
    __shared__ float E[8][64];
    __shared__ float W1s[8][96];
    __shared__ float h1t[96][64];
    __shared__ float W2t[32][192];
    __shared__ float b1s[96], b2s[192];

    const int t = threadIdx.x;
    const int b = blockIdx.x >> 5;
    const int nb = (blockIdx.x & 31) << 4;
    const float* Xb = X + (size_t)b * NN * 4;

    for (int i = t; i < 8 * 96; i += 256) W1s[i / 96][i % 96] = W1[i];
    if (t < 96) b1s[t] = b1[t];
    if (t < 192) b2s[t] = b2[t];

    if (t < 64) {
        const int e = t;
        const int node = nb + (e >> 2);
        const int j = nidx[((size_t)b * NN + node) * KNNK + (e & 3)];
        const float4 xi = *(const float4*)(Xb + (size_t)node * 4);
        const float4 xj = *(const float4*)(Xb + (size_t)j * 4);
        E[0][e] = xi.x; E[1][e] = xi.y; E[2][e] = xi.z; E[3][e] = xi.w;
        E[4][e] = xj.x - xi.x; E[5][e] = xj.y - xi.y; E[6][e] = xj.z - xi.z; E[7][e] = xj.w - xi.w;
    }
    __syncthreads();

    const int rg = t & 15;
    {   // GEMM1
        const int cg = t >> 4;
        float acc[4][6];
#pragma unroll
        for (int r = 0; r < 4; r++)
#pragma unroll
            for (int c = 0; c < 6; c++) acc[r][c] = 0.0f;
#pragma unroll
        for (int k = 0; k < 8; k++) {
            const float4 e4 = *(const float4*)&E[k][rg * 4];
            const float er[4] = {e4.x, e4.y, e4.z, e4.w};
            float wc[6];
#pragma unroll
            for (int c = 0; c < 6; c++) wc[c] = W1s[k][cg * 6 + c];
#pragma unroll
            for (int r = 0; r < 4; r++)
#pragma unroll
                for (int c = 0; c < 6; c++) acc[r][c] += er[r] * wc[c];
        }
#pragma unroll
        for (int c = 0; c < 6; c++) {
            const int col = cg * 6 + c;
            const float bias = b1s[col];
#pragma unroll
            for (int r = 0; r < 4; r++) h1t[col][rg * 4 + r] = lrelu(acc[r][c] + bias);
        }
    }
    __syncthreads();

    {   // GEMM2
        const int cg = t >> 4;
        float acc[4][12];
#pragma unroll
        for (int r = 0; r < 4; r++)
#pragma unroll
            for (int c = 0; c < 12; c++) acc[r][c] = 0.0f;
        for (int kt = 0; kt < 3; kt++) {
            for (int i = t; i < 32 * 192; i += 256)
                W2t[i / 192][i % 192] = W2[(size_t)(kt * 32 + i / 192) * 192 + i % 192];
            __syncthreads();
#pragma unroll
            for (int kk = 0; kk < 32; kk++) {
                const int k = kt * 32 + kk;
                const float4 e4 = *(const float4*)&h1t[k][rg * 4];
                const float er[4] = {e4.x, e4.y, e4.z, e4.w};
                float wc[12];
#pragma unroll
                for (int c = 0; c < 12; c += 4) {
                    const float4 w4 = *(const float4*)&W2t[kk][cg * 12 + c];
                    wc[c] = w4.x; wc[c + 1] = w4.y; wc[c + 2] = w4.z; wc[c + 3] = w4.w;
                }
#pragma unroll
                for (int r = 0; r < 4; r++)
#pragma unroll
                    for (int c = 0; c < 12; c++) acc[r][c] += er[r] * wc[c];
            }
            __syncthreads();
        }
        const int node = nb + rg;
        float res[12];
#pragma unroll
        for (int c = 0; c < 12; c++) {
            const float bias = b2s[cg * 12 + c];
            res[c] = lrelu(acc[0][c] + bias) + lrelu(acc[1][c] + bias)
                   + lrelu(acc[2][c] + bias) + lrelu(acc[3][c] + bias);
        }
        float* op = out + ((size_t)b * NN + node) * 192 + cg * 12;
#pragma unroll
        for (int c = 0; c < 12; c += 4) {
            float4 o; o.x = res[c]; o.y = res[c + 1]; o.z = res[c + 2]; o.w = res[c + 3];
            *(float4*)(op + c) = o;
        }
    }
}

// ---------------------------------------------------------------- weight preps
// conv W1 -> Wcat 3 bf16 planes [512 col][192 k] (all conv layers)
__global__ void wprep3_kernel(const float* __restrict__ W1, unsigned short* __restrict__ wcat3) {
    const int idx = blockIdx.x * 256 + threadIdx.x;   // 512*192
    const int c = idx / 192, k = idx % 192;
    float v = 0.0f;
    if (c < 252) v = W1[(size_t)k * 252 + c] - W1[(size_t)(192 + k) * 252 + c];
    else if (c >= 256 && c < 508) v = W1[(size_t)(192 + k) * 252 + (c - 256)];
    const unsigned short c0 = f2bf(v);
    const float r1 = v - bf2f(c0);
    const unsigned short c1 = f2bf(r1);
    const float r2 = r1 - bf2f(c1);
    wcat3[idx] = c0;
    wcat3[98304 + idx] = c1;
    wcat3[196608 + idx] = f2bf(r2);
}

// conv W2 -> 3 bf16 planes [192][256] (for conve)
__global__ void wprep2_kernel(const float* __restrict__ W2, unsigned short* __restrict__ w2p) {
    const int idx = blockIdx.x * 256 + threadIdx.x;  // 192*256
    const int col = idx >> 8, k = idx & 255;
    const float v = (k < 252) ? W2[(size_t)k * 192 + col] : 0.0f;
    const unsigned short c0 = f2bf(v);
    const float r1 = v - bf2f(c0);
    const unsigned short c1 = f2bf(r1);
    const float r2 = r1 - bf2f(c1);
    w2p[idx] = c0;
    w2p[49152 + idx] = c1;
    w2p[98304 + idx] = f2bf(r2);
}

// ---------------------------------------------------------------- PQ node GEMM bf16x6 MFMA (all conv layers; validated R7)
__global__ __launch_bounds__(256, 3)
void pq_mfma_kernel(const float* __restrict__ X,
                    const unsigned short* __restrict__ wcat3,  // 3 planes [512][192]
                    float* __restrict__ PQ)
{
    __shared__ float Xt[32][66];
    __shared__ unsigned short Bl[3][128][32];

    const int t = threadIdx.x;
    const int m0 = (blockIdx.x >> 2) << 6;
    const int n0 = (blockIdx.x & 3) << 7;
    const int wv = t >> 6, l = t & 63, lm = l & 15, g = l >> 4;
    const int srow = t >> 2, skq = (t & 3) << 3;

    f4v acc[8];
#pragma unroll
    for (int i = 0; i < 8; i++) acc[i] = (f4v){0.0f, 0.0f, 0.0f, 0.0f};

    for (int kt = 0; kt < 6; ++kt) {
        const int k0 = kt << 5;
        {   // stage X fp32
            const float* sp = &X[(size_t)(m0 + srow) * 192 + k0 + skq];
            const float4 xa = *(const float4*)sp;
            const float4 xb = *(const float4*)(sp + 4);
            Xt[skq + 0][srow] = xa.x; Xt[skq + 1][srow] = xa.y;
            Xt[skq + 2][srow] = xa.z; Xt[skq + 3][srow] = xa.w;
            Xt[skq + 4][srow] = xb.x; Xt[skq + 5][srow] = xb.y;
            Xt[skq + 6][srow] = xb.z; Xt[skq + 7][srow] = xb.w;
        }
#pragma unroll
        for (int it = 0; it < 6; ++it) {   // stage B: 3 planes x 128 cols x 4 chunks
            const int p = it >> 1;
            const int col = (it & 1) * 64 + (t >> 2);
            const int chunk = t & 3;
            const int pos = chunk ^ ((col >> 1) & 3);
            *(s8v*)&Bl[p][col][pos * 8] =
                *(const s8v*)&wcat3[(size_t)p * 98304 + (size_t)(n0 + col) * 192 + k0 + chunk * 8];
        }
        __syncthreads();

        s8v A0, A1, A2;
#pragma unroll
        for (int i = 0; i < 8; ++i) {
            const float hv = Xt[g * 8 + i][wv * 16 + lm];
            const unsigned short c0 = f2bf(hv);
            const float r1 = hv - bf2f(c0);
            const unsigned short c1 = f2bf(r1);
            const float r2 = r1 - bf2f(c1);
            A0[i] = (short)c0;
            A1[i] = (short)c1;
            A2[i] = (short)f2bf(r2);
        }
#pragma unroll
        for (int nt = 0; nt < 8; ++nt) {
            const int col = nt * 16 + lm;
            const int pos = g ^ ((col >> 1) & 3);
            const s8v B0 = *(const s8v*)&Bl[0][col][pos * 8];
            const s8v B1 = *(const s8v*)&Bl[1][col][pos * 8];
            const s8v B2 = *(const s8v*)&Bl[2][col][pos * 8];
            acc[nt] = __builtin_amdgcn_mfma_f32_16x16x32_bf16(A0, B0, acc[nt], 0, 0, 0);
            acc[nt] = __builtin_amdgcn_mfma_f32_16x16x32_bf16(A0, B1, acc[nt], 0, 0, 0);
            acc[nt] = __builtin_amdgcn_mfma_f32_16x16x32_bf16(A1, B0, acc[nt], 0, 0, 0);
            acc[nt] = __builtin_amdgcn_mfma_f32_16x16x32_bf16(A1, B1, acc[nt], 0, 0, 0);
            acc[nt] = __builtin_amdgcn_mfma_f32_16x16x32_bf16(A0, B2, acc[nt], 0, 0, 0);
            acc[nt] = __builtin_amdgcn_mfma_f32_16x16x32_bf16(A2, B0, acc[nt], 0, 0, 0);
        }
        __syncthreads();
    }
#pragma unroll
    for (int nt = 0; nt < 8; ++nt) {
        const int col = n0 + nt * 16 + lm;
#pragma unroll
        for (int r = 0; r < 4; ++r) {
            PQ[(size_t)(m0 + wv * 16 + g * 4 + r) * 512 + col] = acc[nt][r];
        }
    }
}

// ---------------------------------------------------------------- conv2/3/4 edge phase: bf16x6 MFMA (bit-exact R4)
__global__ __launch_bounds__(256, 2)
void conv234e_mfma_kernel(const float* __restrict__ PQ,
                          const int* __restrict__ nidx,
                          const unsigned short* __restrict__ w2p,  // 3 planes [192][256]
                          const float* __restrict__ b1,
                          const float* __restrict__ b2,
                          float* __restrict__ out)
{
    __shared__ float h1c[32][132];
    __shared__ unsigned short Bl[3][192][32];
    __shared__ float b1s[256];
    __shared__ float b2s[192];

    const int t = threadIdx.x;
    const int nodebase = (blockIdx.x >> 4) << 9;
    const int nb = (blockIdx.x & 15) << 5;

    b1s[t] = (t < 252) ? b1[t] : 0.0f;
    if (t < 192) b2s[t] = b2[t];

    const int m = t >> 3, s = t & 7;
    const int4 jj = *(const int4*)&nidx[(size_t)(nodebase + nb + m) * 4];
    const float* Prow = PQ + (size_t)(nodebase + nb + m) * 512;
    const float* Q0 = PQ + (size_t)(nodebase + jj.x) * 512 + 256;
    const float* Q1 = PQ + (size_t)(nodebase + jj.y) * 512 + 256;
    const float* Q2 = PQ + (size_t)(nodebase + jj.z) * 512 + 256;
    const float* Q3 = PQ + (size_t)(nodebase + jj.w) * 512 + 256;

    const int bcol = t >> 2, bchk = t & 3;
    const int w = t >> 6, l = t & 63, lm = l & 15, g = l >> 4;
    const int mhalf = w & 1, nhalf = w >> 1;

    f4v acc[4][6];
#pragma unroll
    for (int i = 0; i < 4; i++)
#pragma unroll
        for (int j = 0; j < 6; j++) acc[i][j] = (f4v){0.0f, 0.0f, 0.0f, 0.0f};

    __syncthreads();

    for (int kt = 0; kt < 8; ++kt) {
        const int k0 = kt << 5;
        {   // stage A: h1 fp32, 4 k x 4 edges per thread
            const int kq = s << 2;
            const float4 pv = *(const float4*)&Prow[k0 + kq];
            const float4 bb = *(const float4*)&b1s[k0 + kq];
            const float4 qa = *(const float4*)&Q0[k0 + kq];
            const float4 qb = *(const float4*)&Q1[k0 + kq];
            const float4 qc = *(const float4*)&Q2[k0 + kq];
            const float4 qd = *(const float4*)&Q3[k0 + kq];
            const float p0 = pv.x + bb.x, p1 = pv.y + bb.y, p2 = pv.z + bb.z, p3 = pv.w + bb.w;
            float4 h;
            h.x = lrelu(p0 + qa.x); h.y = lrelu(p0 + qb.x); h.z = lrelu(p0 + qc.x); h.w = lrelu(p0 + qd.x);
            *(float4*)&h1c[kq + 0][m * 4] = h;
            h.x = lrelu(p1 + qa.y); h.y = lrelu(p1 + qb.y); h.z = lrelu(p1 + qc.y); h.w = lrelu(p1 + qd.y);
            *(float4*)&h1c[kq + 1][m * 4] = h;
            h.x = lrelu(p2 + qa.z); h.y = lrelu(p2 + qb.z); h.z = lrelu(p2 + qc.z); h.w = lrelu(p2 + qd.z);
            *(float4*)&h1c[kq + 2][m * 4] = h;
            h.x = lrelu(p3 + qa.w); h.y = lrelu(p3 + qb.w); h.z = lrelu(p3 + qc.w); h.w = lrelu(p3 + qd.w);
            *(float4*)&h1c[kq + 3][m * 4] = h;
        }
#pragma unroll
        for (int it = 0; it < 9; ++it) {
            const int p = it / 3;
            const int col = (it % 3) * 64 + bcol;
            const int pos = bchk ^ ((col >> 1) & 3);
            *(s8v*)&Bl[p][col][pos * 8] =
                *(const s8v*)&w2p[(size_t)p * 49152 + (size_t)col * 256 + k0 + bchk * 8];
        }
        __syncthreads();

        s8v A0[4], A1[4], A2[4];
#pragma unroll
        for (int mt = 0; mt < 4; ++mt) {
            const int edge = mhalf * 64 + mt * 16 + lm;
#pragma unroll
            for (int i = 0; i < 8; ++i) {
                const float hv = h1c[g * 8 + i][edge];
                const unsigned short c0 = f2bf(hv);
                const float r1 = hv - bf2f(c0);
                const unsigned short c1 = f2bf(r1);
                const float r2 = r1 - bf2f(c1);
                A0[mt][i] = (short)c0;
                A1[mt][i] = (short)c1;
                A2[mt][i] = (short)f2bf(r2);
            }
        }
#pragma unroll
        for (int nt = 0; nt < 6; ++nt) {
            const int col = nhalf * 96 + nt * 16 + lm;
            const int pos = g ^ ((col >> 1) & 3);
            const s8v B0 = *(const s8v*)&Bl[0][col][pos * 8];
            const s8v B1 = *(const s8v*)&Bl[1][col][pos * 8];
            const s8v B2 = *(const s8v*)&Bl[2][col][pos * 8];
#pragma unroll
            for (int mt = 0; mt < 4; ++mt) {
                acc[mt][nt] = __builtin_amdgcn_mfma_f32_16x16x32_bf16(A0[mt], B0, acc[mt][nt], 0, 0, 0);
                acc[mt][nt] = __builtin_amdgcn_mfma_f32_16x16x32_bf16(A0[mt], B1, acc[mt][nt], 0, 0, 0);
                acc[mt][nt] = __builtin_amdgcn_mfma_f32_16x16x32_bf16(A1[mt], B0, acc[mt][nt], 0, 0, 0);
                acc[mt][nt] = __builtin_amdgcn_mfma_f32_16x16x32_bf16(A1[mt], B1, acc[mt][nt], 0, 0, 0);
                acc[mt][nt] = __builtin_amdgcn_mfma_f32_16x16x32_bf16(A0[mt], B2, acc[mt][nt], 0, 0, 0);
                acc[mt][nt] = __builtin_amdgcn_mfma_f32_16x16x32_bf16(A2[mt], B0, acc[mt][nt], 0, 0, 0);
            }
        }
        __syncthreads();
    }

#pragma unroll
    for (int mt = 0; mt < 4; ++mt) {
        const int node = nodebase + nb + mhalf * 16 + mt * 4 + g;
#pragma unroll
        for (int nt = 0; nt < 6; ++nt) {
            const int col = nhalf * 96 + nt * 16 + lm;
            const float bias = b2s[col];
            const f4v v = acc[mt][nt];
            out[(size_t)node * 192 + col] =
                lrelu(v[0] + bias) + lrelu(v[1] + bias) + lrelu(v[2] + bias) + lrelu(v[3] + bias);
        }
    }
}

// ---------------------------------------------------------------- nn weight preps
__global__ void nn1prep_kernel(const float* __restrict__ W1,
                               unsigned short* __restrict__ hi,
                               unsigned short* __restrict__ lo) {
    const int idx = blockIdx.x * 256 + threadIdx.x;  // 256*800
    const int col = idx / 800, k = idx % 800;
    float v = 0.0f;
    if (col < 252) {
        if (k < 4) v = W1[(size_t)k * 252 + col];
        else if (k >= 32) {
            const int s = (k - 32) / 192, kk = (k - 32) % 192;
            v = W1[(size_t)(4 + s * 192 + kk) * 252 + col];
        }
    }
    const unsigned short h = f2bf(v);
    hi[idx] = h;
    lo[idx] = f2bf(v - bf2f(h));
}

__global__ void nn2prep_kernel(const float* __restrict__ W2,
                               unsigned short* __restrict__ hi,
                               unsigned short* __restrict__ lo) {
    const int idx = blockIdx.x * 256 + threadIdx.x;  // 192*256
    const int col = idx >> 8, k = idx & 255;
    const float v = (k < 252) ? W2[(size_t)k * 192 + col] : 0.0f;
    const unsigned short h = f2bf(v);
    hi[idx] = h;
    lo[idx] = f2bf(v - bf2f(h));
}

// ---------------------------------------------------------------- nn1 MFMA (bf16x3) + LDS B staging
__global__ __launch_bounds__(256)
void nn1_mfma_kernel(const float* __restrict__ x,
                     const float* __restrict__ a,
                     const float* __restrict__ bf,
                     const float* __restrict__ cf,
                     const float* __restrict__ df,
                     const unsigned short* __restrict__ w1t_hi,
                     const unsigned short* __restrict__ w1t_lo,
                     const float* __restrict__ b1,
                     float* __restrict__ h1)
{
    __shared__ unsigned short Bl[2][256][32];
    const int t = threadIdx.x;
    const int wv = t >> 6, l = t & 63, lm = l & 15, g = l >> 4;
    const int m0 = blockIdx.x << 6;
    const int row = m0 + wv * 16 + lm;
    const int scol = t >> 2, schunk = t & 3;

    f4v acc[16];
#pragma unroll
    for (int i = 0; i < 16; i++) acc[i] = (f4v){0.0f, 0.0f, 0.0f, 0.0f};

    const float* segp[4] = {a, bf, cf, df};

#pragma unroll 1
    for (int step = 0; step < 25; ++step) {
        const int kb0 = step * 32;
        {   // stage B: 2 planes x 256 cols x 4 chunks (8 x 16B per thread)
#pragma unroll
            for (int it = 0; it < 8; ++it) {
                const int p = it >> 2;
                const int col = (it & 3) * 64 + scol;
                const int pos = schunk ^ ((col >> 1) & 3);
                const unsigned short* src = (p == 0) ? w1t_hi : w1t_lo;
                *(s8v*)&Bl[p][col][pos * 8] =
                    *(const s8v*)&src[(size_t)col * 800 + kb0 + schunk * 8];
            }
        }
        float v[8];
        if (step == 0) {
            if (g == 0) {
                const float4 xv = *(const float4*)&x[(size_t)row * 4];
                v[0] = xv.x; v[1] = xv.y; v[2] = xv.z; v[3] = xv.w;
                v[4] = v[5] = v[6] = v[7] = 0.0f;
            } else {
#pragma unroll
                for (int i = 0; i < 8; i++) v[i] = 0.0f;
            }
        } else {
            const int s = (step - 1) / 6;
            const int kin = ((step - 1) % 6) * 32 + g * 8;
            const float* sp = segp[s] + (size_t)row * 192 + kin;
            const float4 a0 = *(const float4*)sp;
            const float4 a1 = *(const float4*)(sp + 4);
            v[0] = a0.x; v[1] = a0.y; v[2] = a0.z; v[3] = a0.w;
            v[4] = a1.x; v[5] = a1.y; v[6] = a1.z; v[7] = a1.w;
        }
        s8v ahi, alo;
#pragma unroll
        for (int i = 0; i < 8; i++) {
            const unsigned short h = f2bf(v[i]);
            ahi[i] = (short)h;
            alo[i] = (short)f2bf(v[i] - bf2f(h));
        }
        __syncthreads();
#pragma unroll
        for (int nt = 0; nt < 16; ++nt) {
            const int col = nt * 16 + lm;
            const int pos = g ^ ((col >> 1) & 3);
            const s8v bhi = *(const s8v*)&Bl[0][col][pos * 8];
            const s8v blo = *(const s8v*)&Bl[1][col][pos * 8];
            acc[nt] = __builtin_amdgcn_mfma_f32_16x16x32_bf16(ahi, bhi, acc[nt], 0, 0, 0);
            acc[nt] = __builtin_amdgcn_mfma_f32_16x16x32_bf16(ahi, blo, acc[nt], 0, 0, 0);
            acc[nt] = __builtin_amdgcn_mfma_f32_16x16x32_bf16(alo, bhi, acc[nt], 0, 0, 0);
        }
        __syncthreads();
    }
#pragma unroll
    for (int nt = 0; nt < 16; ++nt) {
        const int col = nt * 16 + lm;
        const float bias = (col < 252) ? b1[col] : 0.0f;
#pragma unroll
        for (int r = 0; r < 4; ++r) {
            const int orow = m0 + wv * 16 + g * 4 + r;
            h1[(size_t)orow * 256 + col] = lrelu(acc[nt][r] + bias);
        }
    }
}

// ---------------------------------------------------------------- nn2 MFMA + fused pooling + LDS B staging
__global__ __launch_bounds__(256)
void nn2pool_mfma_kernel(const float* __restrict__ h1,
                         const unsigned short* __restrict__ n2t_hi,
                         const unsigned short* __restrict__ n2t_lo,
                         const float* __restrict__ b2,
                         int grow0,
                         float* __restrict__ partials)
{
    __shared__ unsigned short Bl[2][192][32];
    __shared__ float red[4][3][192];
    const int t = threadIdx.x;
    const int wv = t >> 6, l = t & 63, lm = l & 15, g = l >> 4;
    const int m0 = blockIdx.x << 6;
    const int row = m0 + wv * 16 + lm;
    const int scol = t >> 2, schunk = t & 3;

    f4v acc[12];
#pragma unroll
    for (int i = 0; i < 12; i++) acc[i] = (f4v){0.0f, 0.0f, 0.0f, 0.0f};

#pragma unroll 1
    for (int step = 0; step < 8; ++step) {
        const int kb0 = step * 32;
        {   // stage B: 2 planes x 192 cols x 4 chunks (6 x 16B per thread)
#pragma unroll
            for (int it = 0; it < 6; ++it) {
                const int p = it / 3;
                const int col = (it % 3) * 64 + scol;
                const int pos = schunk ^ ((col >> 1) & 3);
                const unsigned short* src = (p == 0) ? n2t_hi : n2t_lo;
                *(s8v*)&Bl[p][col][pos * 8] =
                    *(const s8v*)&src[(size_t)col * 256 + kb0 + schunk * 8];
            }
        }
        const float* sp = h1 + (size_t)row * 256 + kb0 + g * 8;
        const float4 a0 = *(const float4*)sp;
        const float4 a1 = *(const float4*)(sp + 4);
        const float v[8] = {a0.x, a0.y, a0.z, a0.w, a1.x, a1.y, a1.z, a1.w};
        s8v ahi, alo;
#pragma unroll
        for (int i = 0; i < 8; i++) {
            const unsigned short h = f2bf(v[i]);
            ahi[i] = (short)h;
            alo[i] = (short)f2bf(v[i] - bf2f(h));
        }
        __syncthreads();
#pragma unroll
        for (int nt = 0; nt < 12; ++nt) {
            const int col = nt * 16 + lm;
            const int pos = g ^ ((col >> 1) & 3);
            const s8v bhi = *(const s8v*)&Bl[0][col][pos * 8];
            const s8v blo = *(const s8v*)&Bl[1][col][pos * 8];
            acc[nt] = __builtin_amdgcn_mfma_f32_16x16x32_bf16(ahi, bhi, acc[nt], 0, 0, 0);
            acc[nt] = __builtin_amdgcn_mfma_f32_16x16x32_bf16(ahi, blo, acc[nt], 0, 0, 0);
            acc[nt] = __builtin_amdgcn_mfma_f32_16x16x32_bf16(alo, bhi, acc[nt], 0, 0, 0);
        }
        __syncthreads();
    }

    float mx[12], mn[12], sm[12];
#pragma unroll
    for (int nt = 0; nt < 12; ++nt) {
        const float bias = b2[nt * 16 + lm];
        const float v0 = acc[nt][0] + bias, v1 = acc[nt][1] + bias;
        const float v2 = acc[nt][2] + bias, v3 = acc[nt][3] + bias;
        mx[nt] = fmaxf(fmaxf(v0, v1), fmaxf(v2, v3));
        mn[nt] = fminf(fminf(v0, v1), fminf(v2, v3));
        sm[nt] = (v0 + v1) + (v2 + v3);
    }
#pragma unroll
    for (int nt = 0; nt < 12; ++nt) {
        mx[nt] = fmaxf(mx[nt], __shfl_xor(mx[nt], 16));
        mn[nt] = fminf(mn[nt], __shfl_xor(mn[nt], 16));
        sm[nt] += __shfl_xor(sm[nt], 16);
        mx[nt] = fmaxf(mx[nt], __shfl_xor(mx[nt], 32));
        mn[nt] = fminf(mn[nt], __shfl_xor(mn[nt], 32));
        sm[nt] += __shfl_xor(sm[nt], 32);
    }
    if (l < 16) {
#pragma unroll
        for (int nt = 0; nt < 12; ++nt) {
            const int col = nt * 16 + lm;
            red[wv][0][col] = mx[nt];
            red[wv][1][col] = mn[nt];
            red[wv][2][col] = sm[nt];
        }
    }
    __syncthreads();
    if (t < 192) {
        const int grow = grow0 + m0;
        float* pp = partials + (((size_t)(grow >> 9) * 8 + ((grow >> 6) & 7)) * 3) * 192;
        pp[t]       = fmaxf(fmaxf(red[0][0][t], red[1][0][t]), fmaxf(red[2][0][t], red[3][0][t]));
        pp[192 + t] = fminf(fminf(red[0][1][t], red[1][1][t]), fminf(red[2][1][t], red[3][1][t]));
        pp[384 + t] = (red[0][2][t] + red[1][2][t]) + (red[2][2][t] + red[3][2][t]);
    }
}

// ---------------------------------------------------------------- pool reduce + head
__global__ void pool_reduce_kernel(const float* __restrict__ partials, float* __restrict__ pooledL) {
    const int b = blockIdx.x, c = threadIdx.x;
    float mx = -3.4e38f, mn = 3.4e38f, sm = 0.0f;
    for (int blk = 0; blk < 8; blk++) {
        const float* pp = partials + ((size_t)b * 8 + blk) * 3 * 192;
        mx = fmaxf(mx, pp[c]);
        mn = fminf(mn, pp[192 + c]);
        sm += pp[384 + c];
    }
    float* o = pooledL + (size_t)b * 768;
    o[c] = lrelu(mx);
    o[192 + c] = lrelu(mn);
    o[384 + c] = lrelu(sm);
    o[576 + c] = lrelu(sm * (1.0f / 512.0f));
}

__global__ __launch_bounds__(128)
void head_kernel(const float* __restrict__ pooledL,
                 const float* __restrict__ W3, const float* __restrict__ b3,
                 const float* __restrict__ W4, const float* __restrict__ b4,
                 float* __restrict__ out) {
    __shared__ float pl[768];
    __shared__ float h3[96];
    const int b = blockIdx.x, t = threadIdx.x;
    for (int i = t; i < 768; i += 128) pl[i] = pooledL[(size_t)b * 768 + i];
    __syncthreads();
    if (t < 96) {
        float acc = b3[t];
        for (int k = 0; k < 768; k++) acc += pl[k] * W3[(size_t)k * 96 + t];
        h3[t] = lrelu(acc);
    }
    __syncthreads();
    if (t == 0) {
        float s2 = b4[0];
        for (int o = 0; o < 96; o++) s2 += h3[o] * W4[o];
        out[b] = s2;
    }
}

// ---------------------------------------------------------------- launch
extern "C" void kernel_launch(void* const* d_in, const int* in_sizes, int n_in,
                              void* d_out, int out_size, void* d_ws, size_t ws_size,
                              hipStream_t stream) {
    const float* x    = (const float*)d_in[0];
    const float* c1w1 = (const float*)d_in[1];
    const float* c1b1 = (const float*)d_in[2];
    const float* c1w2 = (const float*)d_in[3];
    const float* c1b2 = (const float*)d_in[4];
    const float* cw1[3] = {(const float*)d_in[5], (const float*)d_in[9],  (const float*)d_in[13]};
    const float* cb1[3] = {(const float*)d_in[6], (const float*)d_in[10], (const float*)d_in[14]};
    const float* cw2[3] = {(const float*)d_in[7], (const float*)d_in[11], (const float*)d_in[15]};
    const float* cb2[3] = {(const float*)d_in[8], (const float*)d_in[12], (const float*)d_in[16]};
    const float* nn1w = (const float*)d_in[17];
    const float* nn1b = (const float*)d_in[18];
    const float* nn2w = (const float*)d_in[19];
    const float* nn2b = (const float*)d_in[20];
    const float* nn3w = (const float*)d_in[21];
    const float* nn3b = (const float*)d_in[22];
    const float* nn4w = (const float*)d_in[23];
    const float* nn4b = (const float*)d_in[24];
    float* out = (float*)d_out;

    // workspace layout (float units)
    const size_t featN  = (size_t)BB * NN * 192;
    const size_t idx_f  = (size_t)BB * NN * KNNK;
    const size_t part_f = (size_t)BB * 8 * 3 * 192;
    const size_t pool_f = (size_t)BB * 768;
    const size_t w1t_f   = (size_t)256 * 800 / 2;    // ushort plane in float units
    const size_t n2t_f   = (size_t)192 * 256 / 2;
    const size_t w2p_f   = (size_t)3 * 192 * 256 / 2;
    const size_t wcat3_f = (size_t)3 * 512 * 192 / 2;

    float* abuf = (float*)d_ws;
    float* bbuf = abuf + featN;
    float* cbuf = bbuf + featN;
    float* dbuf = cbuf + featN;
    int*   idxb = (int*)(dbuf + featN);
    float* partials = (float*)(idxb + idx_f);
    float* pooledL = partials + part_f;
    float* base = pooledL + pool_f;
    unsigned short* w1t_hi = (unsigned short*)base;
    unsigned short* w1t_lo = (unsigned short*)(base + w1t_f);
    unsigned short* n2t_hi = (unsigned short*)(base + 2 * w1t_f);
    unsigned short* n2t_lo = (unsigned short*)(base + 2 * w1t_f + n2t_f);
    unsigned short* w2p    = (unsigned short*)(base + 2 * w1t_f + 2 * n2t_f);
    unsigned short* wcat3  = (unsigned short*)(base + 2 * w1t_f + 2 * n2t_f + w2p_f);
    float* pqbuf = base + 2 * w1t_f + 2 * n2t_f + w2p_f + wcat3_f;

    const size_t fixed_f = 4 * featN + idx_f + part_f + pool_f
                         + 2 * w1t_f + 2 * n2t_f + w2p_f + wcat3_f;
    int CB = BB;
    while (CB > 1) {
        const size_t need = (fixed_f + (size_t)CB * NN * 512) * 4;
        if (need <= ws_size) break;
        CB >>= 1;
    }
    const int nchunks = BB / CB;

    float* feats[4] = {abuf, bbuf, cbuf, dbuf};

    knn_kernel<<<BB, 512, 0, stream>>>(x, 4, idxb);
    conv1_kernel<<<BB * 32, 256, 0, stream>>>(x, idxb, c1w1, c1b1, c1w2, c1b2, abuf);

    for (int L = 0; L < 3; ++L) {
        const float* fin = feats[L];
        float* fout = feats[L + 1];
        knn_kernel<<<BB, 512, 0, stream>>>(fin, 192, idxb);
        wprep3_kernel<<<(512 * 192) / 256, 256, 0, stream>>>(cw1[L], wcat3);
        wprep2_kernel<<<(192 * 256) / 256, 256, 0, stream>>>(cw2[L], w2p);
        for (int ch = 0; ch < nchunks; ++ch) {
            const size_t roff = (size_t)ch * CB * NN;
            pq_mfma_kernel<<<CB * 32, 256, 0, stream>>>(fin + roff * 192, wcat3, pqbuf);
            conv234e_mfma_kernel<<<CB * 16, 256, 0, stream>>>(pqbuf, idxb + roff * KNNK,
                                                              w2p, cb1[L], cb2[L],
                                                              fout + roff * 192);
        }
    }

    // nn phase (MFMA bf16x3 + LDS B staging); h1 reuses pqbuf
    nn1prep_kernel<<<(256 * 800) / 256, 256, 0, stream>>>(nn1w, w1t_hi, w1t_lo);
    nn2prep_kernel<<<(192 * 256) / 256, 256, 0, stream>>>(nn2w, n2t_hi, n2t_lo);
    float* h1buf = pqbuf;
    for (int ch = 0; ch < nchunks; ++ch) {
        const size_t roff = (size_t)ch * CB * NN;
        nn1_mfma_kernel<<<CB * 8, 256, 0, stream>>>(x + roff * 4,
                                                    abuf + roff * 192, bbuf + roff * 192,
                                                    cbuf + roff * 192, dbuf + roff * 192,
                                                    w1t_hi, w1t_lo, nn1b, h1buf);
        nn2pool_mfma_kernel<<<CB * 8, 256, 0, stream>>>(h1buf, n2t_hi, n2t_lo, nn2b,
                                                        (int)roff, partials);
    }
    pool_reduce_kernel<<<BB, 192, 0, stream>>>(partials, pooledL);
    head_kernel<<<BB, 128, 0, stream>>>(pooledL, nn3w, nn3b, nn4w, nn4b, out);
}